// Round 1
// baseline (665.515 us; speedup 1.0000x reference)
//
#include <hip/hip_runtime.h>
#include <hip/hip_bf16.h>
#include <math.h>

#define NTOK 12800
#define HD 256
#define SOUT (NTOK * HD)

// ---------------------------------------------------------------------------
// reparam: mu = A@Wmu + bmu ; sig = exp(A@Wsg + bsg) ; z = mu + sig*noise
// tile 64x64, BK=32, 256 thr, 4x4 per thread
// ---------------------------------------------------------------------------
__global__ __launch_bounds__(256) void reparam_kernel(
    const float* __restrict__ A,
    const float* __restrict__ Wmu, const float* __restrict__ bmu,
    const float* __restrict__ Wsg, const float* __restrict__ bsg,
    const float* __restrict__ noise,
    float* __restrict__ out_mu, float* __restrict__ out_sig,
    float* __restrict__ z_out)
{
    __shared__ float As[32][68];  // [k][m]
    __shared__ float W0[32][68];  // [k][n]
    __shared__ float W1[32][68];
    const int n0 = blockIdx.x * 64;
    const int d0 = blockIdx.y * 64;
    const int tid = threadIdx.x;
    const int tx = tid & 15, ty = tid >> 4;
    float accM[4][4] = {}, accS[4][4] = {};

    for (int k0 = 0; k0 < HD; k0 += 32) {
        __syncthreads();
#pragma unroll
        for (int p = 0; p < 2; ++p) {  // A tile 64x32, store transposed
            const int r = (tid >> 3) + p * 32;
            const int c = (tid & 7) * 4;
            const float4 v = *reinterpret_cast<const float4*>(
                &A[(size_t)(n0 + r) * HD + k0 + c]);
            As[c + 0][r] = v.x; As[c + 1][r] = v.y;
            As[c + 2][r] = v.z; As[c + 3][r] = v.w;
        }
#pragma unroll
        for (int p = 0; p < 2; ++p) {  // W tiles 32x64
            const int r = (tid >> 4) + p * 16;
            const int c = (tid & 15) * 4;
            *reinterpret_cast<float4*>(&W0[r][c]) =
                *reinterpret_cast<const float4*>(&Wmu[(size_t)(k0 + r) * HD + d0 + c]);
            *reinterpret_cast<float4*>(&W1[r][c]) =
                *reinterpret_cast<const float4*>(&Wsg[(size_t)(k0 + r) * HD + d0 + c]);
        }
        __syncthreads();
#pragma unroll
        for (int kk = 0; kk < 32; ++kk) {
            float a[4], w0[4], w1[4];
#pragma unroll
            for (int i = 0; i < 4; ++i) a[i] = As[kk][ty * 4 + i];
#pragma unroll
            for (int j = 0; j < 4; ++j) { w0[j] = W0[kk][tx * 4 + j]; w1[j] = W1[kk][tx * 4 + j]; }
#pragma unroll
            for (int i = 0; i < 4; ++i)
#pragma unroll
                for (int j = 0; j < 4; ++j) {
                    accM[i][j] = fmaf(a[i], w0[j], accM[i][j]);
                    accS[i][j] = fmaf(a[i], w1[j], accS[i][j]);
                }
        }
    }
#pragma unroll
    for (int i = 0; i < 4; ++i) {
        const int n = n0 + ty * 4 + i;
#pragma unroll
        for (int j = 0; j < 4; ++j) {
            const int d = d0 + tx * 4 + j;
            const size_t off = (size_t)n * HD + d;
            const float mu = accM[i][j] + bmu[d];
            const float sg = expf(accS[i][j] + bsg[d]);
            out_mu[off] = mu;
            out_sig[off] = sg;
            z_out[off] = fmaf(sg, noise[off], mu);
        }
    }
}

// ---------------------------------------------------------------------------
// gating: one wave per token. logits = z@Wg + bg -> softmax -> top2 -> renorm
// ---------------------------------------------------------------------------
__global__ __launch_bounds__(256) void gate_kernel(
    const float* __restrict__ Z, const float* __restrict__ Wg,
    const float* __restrict__ bg, float* __restrict__ gate)
{
    const int lane = threadIdx.x & 63;
    const int n = blockIdx.x * 4 + (threadIdx.x >> 6);
    const float4 zv = *reinterpret_cast<const float4*>(&Z[(size_t)n * HD + lane * 4]);
    const float zz[4] = { zv.x, zv.y, zv.z, zv.w };
    float lg[8];
#pragma unroll
    for (int e = 0; e < 8; ++e) lg[e] = 0.f;
#pragma unroll
    for (int i = 0; i < 4; ++i) {
        const float* wr = &Wg[(size_t)(lane * 4 + i) * 8];
        const float4 w0 = *reinterpret_cast<const float4*>(wr);
        const float4 w1 = *reinterpret_cast<const float4*>(wr + 4);
        lg[0] = fmaf(zz[i], w0.x, lg[0]); lg[1] = fmaf(zz[i], w0.y, lg[1]);
        lg[2] = fmaf(zz[i], w0.z, lg[2]); lg[3] = fmaf(zz[i], w0.w, lg[3]);
        lg[4] = fmaf(zz[i], w1.x, lg[4]); lg[5] = fmaf(zz[i], w1.y, lg[5]);
        lg[6] = fmaf(zz[i], w1.z, lg[6]); lg[7] = fmaf(zz[i], w1.w, lg[7]);
    }
#pragma unroll
    for (int off = 32; off; off >>= 1)
#pragma unroll
        for (int e = 0; e < 8; ++e) lg[e] += __shfl_down(lg[e], off);

    if (lane == 0) {
        float m = -1e30f;
#pragma unroll
        for (int e = 0; e < 8; ++e) { lg[e] += bg[e]; m = fmaxf(m, lg[e]); }
        float p[8], s = 0.f;
#pragma unroll
        for (int e = 0; e < 8; ++e) { p[e] = expf(lg[e] - m); s += p[e]; }
        const float inv_s = 1.f / s;
#pragma unroll
        for (int e = 0; e < 8; ++e) p[e] *= inv_s;  // softmax weights
        int e1 = 0;
#pragma unroll
        for (int e = 1; e < 8; ++e) if (p[e] > p[e1]) e1 = e;
        int e2 = (e1 == 0) ? 1 : 0;
#pragma unroll
        for (int e = 0; e < 8; ++e) if (e != e1 && p[e] > p[e2]) e2 = e;
        const float denom = 1.f / (p[e1] + p[e2] + 1e-8f);
        float g[8];
#pragma unroll
        for (int e = 0; e < 8; ++e) g[e] = 0.f;
        g[e1] = p[e1] * denom; g[e2] = p[e2] * denom;
        float* gr = &gate[(size_t)n * 8];
        *reinterpret_cast<float4*>(gr)     = make_float4(g[0], g[1], g[2], g[3]);
        *reinterpret_cast<float4*>(gr + 4) = make_float4(g[4], g[5], g[6], g[7]);
    }
}

// ---------------------------------------------------------------------------
// experts: out[n,d] = sum_e gate[n,e] * (Z@Wx[e] + bx[e])[n,d]   (dense loop)
// ---------------------------------------------------------------------------
__global__ __launch_bounds__(256) void expert_kernel(
    const float* __restrict__ Z, const float* __restrict__ Wx,
    const float* __restrict__ bx, const float* __restrict__ gate,
    float* __restrict__ outp)
{
    __shared__ float As[32][68];
    __shared__ float Ws[32][68];
    const int n0 = blockIdx.x * 64;
    const int d0 = blockIdx.y * 64;
    const int tid = threadIdx.x;
    const int tx = tid & 15, ty = tid >> 4;

    float g[4][8];
#pragma unroll
    for (int i = 0; i < 4; ++i) {
        const float* gr = &gate[(size_t)(n0 + ty * 4 + i) * 8];
        const float4 g0 = *reinterpret_cast<const float4*>(gr);
        const float4 g1 = *reinterpret_cast<const float4*>(gr + 4);
        g[i][0] = g0.x; g[i][1] = g0.y; g[i][2] = g0.z; g[i][3] = g0.w;
        g[i][4] = g1.x; g[i][5] = g1.y; g[i][6] = g1.z; g[i][7] = g1.w;
    }

    float acc[4][4] = {};
    for (int e = 0; e < 8; ++e) {
        float acce[4][4] = {};
        const float* We = Wx + (size_t)e * HD * HD;
        for (int k0 = 0; k0 < HD; k0 += 32) {
            __syncthreads();
#pragma unroll
            for (int p = 0; p < 2; ++p) {
                const int r = (tid >> 3) + p * 32;
                const int c = (tid & 7) * 4;
                const float4 v = *reinterpret_cast<const float4*>(
                    &Z[(size_t)(n0 + r) * HD + k0 + c]);
                As[c + 0][r] = v.x; As[c + 1][r] = v.y;
                As[c + 2][r] = v.z; As[c + 3][r] = v.w;
            }
#pragma unroll
            for (int p = 0; p < 2; ++p) {
                const int r = (tid >> 4) + p * 16;
                const int c = (tid & 15) * 4;
                *reinterpret_cast<float4*>(&Ws[r][c]) =
                    *reinterpret_cast<const float4*>(&We[(size_t)(k0 + r) * HD + d0 + c]);
            }
            __syncthreads();
#pragma unroll
            for (int kk = 0; kk < 32; ++kk) {
                float a[4], w[4];
#pragma unroll
                for (int i = 0; i < 4; ++i) a[i] = As[kk][ty * 4 + i];
#pragma unroll
                for (int j = 0; j < 4; ++j) w[j] = Ws[kk][tx * 4 + j];
#pragma unroll
                for (int i = 0; i < 4; ++i)
#pragma unroll
                    for (int j = 0; j < 4; ++j)
                        acce[i][j] = fmaf(a[i], w[j], acce[i][j]);
            }
        }
#pragma unroll
        for (int j = 0; j < 4; ++j) {
            const float be = bx[(size_t)e * HD + d0 + tx * 4 + j];
#pragma unroll
            for (int i = 0; i < 4; ++i)
                acc[i][j] = fmaf(g[i][e], acce[i][j] + be, acc[i][j]);
        }
    }
#pragma unroll
    for (int i = 0; i < 4; ++i) {
        const int n = n0 + ty * 4 + i;
#pragma unroll
        for (int j = 0; j < 4; ++j)
            outp[(size_t)n * HD + d0 + tx * 4 + j] = acc[i][j];
    }
}

// ---------------------------------------------------------------------------
// fuse GEMM: fused_lin = [t_out | i_out] @ Wf + bf      (K = 512)
// ---------------------------------------------------------------------------
__global__ __launch_bounds__(256) void fusegemm_kernel(
    const float* __restrict__ t_out, const float* __restrict__ i_out,
    const float* __restrict__ Wf, const float* __restrict__ bf,
    float* __restrict__ fused)
{
    __shared__ float As[32][68];
    __shared__ float Ws[32][68];
    const int n0 = blockIdx.x * 64;
    const int d0 = blockIdx.y * 64;
    const int tid = threadIdx.x;
    const int tx = tid & 15, ty = tid >> 4;
    float acc[4][4] = {};

    for (int k0 = 0; k0 < 2 * HD; k0 += 32) {
        const float* Abuf = (k0 < HD) ? t_out : i_out;
        const int kloc = k0 & (HD - 1);
        __syncthreads();
#pragma unroll
        for (int p = 0; p < 2; ++p) {
            const int r = (tid >> 3) + p * 32;
            const int c = (tid & 7) * 4;
            const float4 v = *reinterpret_cast<const float4*>(
                &Abuf[(size_t)(n0 + r) * HD + kloc + c]);
            As[c + 0][r] = v.x; As[c + 1][r] = v.y;
            As[c + 2][r] = v.z; As[c + 3][r] = v.w;
        }
#pragma unroll
        for (int p = 0; p < 2; ++p) {
            const int r = (tid >> 4) + p * 16;
            const int c = (tid & 15) * 4;
            *reinterpret_cast<float4*>(&Ws[r][c]) =
                *reinterpret_cast<const float4*>(&Wf[(size_t)(k0 + r) * HD + d0 + c]);
        }
        __syncthreads();
#pragma unroll
        for (int kk = 0; kk < 32; ++kk) {
            float a[4], w[4];
#pragma unroll
            for (int i = 0; i < 4; ++i) a[i] = As[kk][ty * 4 + i];
#pragma unroll
            for (int j = 0; j < 4; ++j) w[j] = Ws[kk][tx * 4 + j];
#pragma unroll
            for (int i = 0; i < 4; ++i)
#pragma unroll
                for (int j = 0; j < 4; ++j)
                    acc[i][j] = fmaf(a[i], w[j], acc[i][j]);
        }
    }
#pragma unroll
    for (int i = 0; i < 4; ++i) {
        const int n = n0 + ty * 4 + i;
#pragma unroll
        for (int j = 0; j < 4; ++j) {
            const int d = d0 + tx * 4 + j;
            fused[(size_t)n * HD + d] = acc[i][j] + bf[d];
        }
    }
}

// ---------------------------------------------------------------------------
// LN -> ReLU -> +item. one wave per row (H = 256, 4 elems/lane)
// ---------------------------------------------------------------------------
__global__ __launch_bounds__(256) void ln_relu_res_kernel(
    const float* __restrict__ fused, const float* __restrict__ g,
    const float* __restrict__ b, const float* __restrict__ item,
    float* __restrict__ fusion)
{
    const int lane = threadIdx.x & 63;
    const int n = blockIdx.x * 4 + (threadIdx.x >> 6);
    const size_t off = (size_t)n * HD + lane * 4;
    const float4 x = *reinterpret_cast<const float4*>(&fused[off]);
    float s = x.x + x.y + x.z + x.w;
    float ss = x.x * x.x + x.y * x.y + x.z * x.z + x.w * x.w;
#pragma unroll
    for (int o = 32; o; o >>= 1) { s += __shfl_xor(s, o); ss += __shfl_xor(ss, o); }
    const float mean = s * (1.f / 256.f);
    const float var = ss * (1.f / 256.f) - mean * mean;
    const float rstd = rsqrtf(var + 1e-5f);
    const float4 gg = *reinterpret_cast<const float4*>(&g[lane * 4]);
    const float4 bb = *reinterpret_cast<const float4*>(&b[lane * 4]);
    const float4 it = *reinterpret_cast<const float4*>(&item[off]);
    float4 o4;
    o4.x = fmaxf((x.x - mean) * rstd * gg.x + bb.x, 0.f) + it.x;
    o4.y = fmaxf((x.y - mean) * rstd * gg.y + bb.y, 0.f) + it.y;
    o4.z = fmaxf((x.z - mean) * rstd * gg.z + bb.z, 0.f) + it.z;
    o4.w = fmaxf((x.w - mean) * rstd * gg.w + bb.w, 0.f) + it.w;
    *reinterpret_cast<float4*>(&fusion[off]) = o4;
}

// ---------------------------------------------------------------------------
extern "C" void kernel_launch(void* const* d_in, const int* in_sizes, int n_in,
                              void* d_out, int out_size, void* d_ws, size_t ws_size,
                              hipStream_t stream)
{
    const float* text    = (const float*)d_in[0];
    const float* img     = (const float*)d_in[1];
    const float* item    = (const float*)d_in[2];
    const float* noise_t = (const float*)d_in[3];
    const float* noise_i = (const float*)d_in[4];
    const float* W_mu_t  = (const float*)d_in[5];
    const float* b_mu_t  = (const float*)d_in[6];
    const float* W_sg_t  = (const float*)d_in[7];
    const float* b_sg_t  = (const float*)d_in[8];
    const float* W_mu_i  = (const float*)d_in[9];
    const float* b_mu_i  = (const float*)d_in[10];
    const float* W_sg_i  = (const float*)d_in[11];
    const float* b_sg_i  = (const float*)d_in[12];
    const float* W_gate  = (const float*)d_in[13];
    const float* b_gate  = (const float*)d_in[14];
    const float* W_texp  = (const float*)d_in[15];
    const float* b_texp  = (const float*)d_in[16];
    const float* W_iexp  = (const float*)d_in[17];
    const float* b_iexp  = (const float*)d_in[18];
    const float* W_fuse  = (const float*)d_in[19];
    const float* b_fuse  = (const float*)d_in[20];
    const float* ln_g    = (const float*)d_in[21];
    const float* ln_b    = (const float*)d_in[22];

    float* out      = (float*)d_out;
    float* fusion   = out;
    float* o_tmu    = out + (size_t)SOUT;
    float* o_tsig   = out + (size_t)2 * SOUT;
    float* o_imu    = out + (size_t)3 * SOUT;
    float* o_isig   = out + (size_t)4 * SOUT;

    float* ws       = (float*)d_ws;
    float* t_z      = ws;
    float* i_z      = ws + (size_t)SOUT;
    float* t_gate   = ws + (size_t)2 * SOUT;
    float* i_gate   = t_gate + (size_t)NTOK * 8;
    float* t_out    = i_gate + (size_t)NTOK * 8;
    float* i_out    = t_out + (size_t)SOUT;
    float* fused_ln = t_z;  // t_z is dead by the time fusegemm runs

    const dim3 gemm_grid(NTOK / 64, HD / 64);  // 200 x 4
    reparam_kernel<<<gemm_grid, 256, 0, stream>>>(
        text, W_mu_t, b_mu_t, W_sg_t, b_sg_t, noise_t, o_tmu, o_tsig, t_z);
    reparam_kernel<<<gemm_grid, 256, 0, stream>>>(
        img, W_mu_i, b_mu_i, W_sg_i, b_sg_i, noise_i, o_imu, o_isig, i_z);

    gate_kernel<<<NTOK / 4, 256, 0, stream>>>(t_z, W_gate, b_gate, t_gate);
    gate_kernel<<<NTOK / 4, 256, 0, stream>>>(i_z, W_gate, b_gate, i_gate);

    expert_kernel<<<gemm_grid, 256, 0, stream>>>(t_z, W_texp, b_texp, t_gate, t_out);
    expert_kernel<<<gemm_grid, 256, 0, stream>>>(i_z, W_iexp, b_iexp, i_gate, i_out);

    fusegemm_kernel<<<gemm_grid, 256, 0, stream>>>(t_out, i_out, W_fuse, b_fuse, fused_ln);

    ln_relu_res_kernel<<<NTOK / 4, 256, 0, stream>>>(fused_ln, ln_g, ln_b, item, fusion);
}

// Round 2
// 254.237 us; speedup vs baseline: 2.6177x; 2.6177x over previous
//
#include <hip/hip_runtime.h>
#include <hip/hip_bf16.h>
#include <math.h>

#define NTOK 12800
#define HD 256
#define SOUT (NTOK * HD)

typedef __attribute__((ext_vector_type(8))) short short8_t;
typedef __attribute__((ext_vector_type(4))) float f32x4;

__device__ __forceinline__ unsigned short f2b(float f) {
    union { float f; unsigned u; } v; v.f = f;
    unsigned r = (v.u + 0x7FFFu + ((v.u >> 16) & 1u)) >> 16;
    return (unsigned short)r;
}

// ---------------------------------------------------------------------------
// reparam: mu = A@Wmu + bmu ; sig = exp(A@Wsg + bsg) ; z = mu + sig*noise
// also emits z as bf16 for the MFMA expert kernel.
// ---------------------------------------------------------------------------
__global__ __launch_bounds__(256) void reparam_kernel(
    const float* __restrict__ A,
    const float* __restrict__ Wmu, const float* __restrict__ bmu,
    const float* __restrict__ Wsg, const float* __restrict__ bsg,
    const float* __restrict__ noise,
    float* __restrict__ out_mu, float* __restrict__ out_sig,
    float* __restrict__ z_out, unsigned short* __restrict__ zb_out)
{
    __shared__ float As[32][68];
    __shared__ float W0[32][68];
    __shared__ float W1[32][68];
    const int n0 = blockIdx.x * 64;
    const int d0 = blockIdx.y * 64;
    const int tid = threadIdx.x;
    const int tx = tid & 15, ty = tid >> 4;
    float accM[4][4] = {}, accS[4][4] = {};

    for (int k0 = 0; k0 < HD; k0 += 32) {
        __syncthreads();
#pragma unroll
        for (int p = 0; p < 2; ++p) {
            const int r = (tid >> 3) + p * 32;
            const int c = (tid & 7) * 4;
            const float4 v = *reinterpret_cast<const float4*>(
                &A[(size_t)(n0 + r) * HD + k0 + c]);
            As[c + 0][r] = v.x; As[c + 1][r] = v.y;
            As[c + 2][r] = v.z; As[c + 3][r] = v.w;
        }
#pragma unroll
        for (int p = 0; p < 2; ++p) {
            const int r = (tid >> 4) + p * 16;
            const int c = (tid & 15) * 4;
            *reinterpret_cast<float4*>(&W0[r][c]) =
                *reinterpret_cast<const float4*>(&Wmu[(size_t)(k0 + r) * HD + d0 + c]);
            *reinterpret_cast<float4*>(&W1[r][c]) =
                *reinterpret_cast<const float4*>(&Wsg[(size_t)(k0 + r) * HD + d0 + c]);
        }
        __syncthreads();
#pragma unroll
        for (int kk = 0; kk < 32; ++kk) {
            float a[4], w0[4], w1[4];
#pragma unroll
            for (int i = 0; i < 4; ++i) a[i] = As[kk][ty * 4 + i];
#pragma unroll
            for (int j = 0; j < 4; ++j) { w0[j] = W0[kk][tx * 4 + j]; w1[j] = W1[kk][tx * 4 + j]; }
#pragma unroll
            for (int i = 0; i < 4; ++i)
#pragma unroll
                for (int j = 0; j < 4; ++j) {
                    accM[i][j] = fmaf(a[i], w0[j], accM[i][j]);
                    accS[i][j] = fmaf(a[i], w1[j], accS[i][j]);
                }
        }
    }
#pragma unroll
    for (int i = 0; i < 4; ++i) {
        const int n = n0 + ty * 4 + i;
        ushort4 zb4;
        float zv[4];
#pragma unroll
        for (int j = 0; j < 4; ++j) {
            const int d = d0 + tx * 4 + j;
            const size_t off = (size_t)n * HD + d;
            const float mu = accM[i][j] + bmu[d];
            const float sg = expf(accS[i][j] + bsg[d]);
            out_mu[off] = mu;
            out_sig[off] = sg;
            zv[j] = fmaf(sg, noise[off], mu);
            z_out[off] = zv[j];
        }
        zb4.x = f2b(zv[0]); zb4.y = f2b(zv[1]); zb4.z = f2b(zv[2]); zb4.w = f2b(zv[3]);
        *reinterpret_cast<ushort4*>(&zb_out[(size_t)n * HD + d0 + tx * 4]) = zb4;
    }
}

// ---------------------------------------------------------------------------
// W transpose+convert: Wt[e][d][k] (bf16) = W[e][k][d] (fp32)
// ---------------------------------------------------------------------------
__global__ __launch_bounds__(256) void transposeW_kernel(
    const float* __restrict__ Wsrc_t, const float* __restrict__ Wsrc_i,
    unsigned short* __restrict__ Wdst_t, unsigned short* __restrict__ Wdst_i)
{
    const float* W = blockIdx.z ? Wsrc_i : Wsrc_t;
    unsigned short* O = blockIdx.z ? Wdst_i : Wdst_t;
    const int e = blockIdx.y;
    const int tk = (blockIdx.x >> 2) * 64;
    const int td = (blockIdx.x & 3) * 64;
    __shared__ float T[64][68];
    const int t = threadIdx.x;
    {
        const int r = t >> 2;
        const int c0 = (t & 3) * 16;
        const float* src = &W[((size_t)e * HD + tk + r) * HD + td + c0];
#pragma unroll
        for (int j = 0; j < 4; ++j)
            *reinterpret_cast<float4*>(&T[r][c0 + j * 4]) =
                *reinterpret_cast<const float4*>(&src[j * 4]);
    }
    __syncthreads();
    {
        const int d = t & 63;
        const int kc = (t >> 6) * 16;
        union { unsigned short s[16]; short8_t v[2]; } u;
#pragma unroll
        for (int j = 0; j < 16; ++j) u.s[j] = f2b(T[kc + j][d]);
        unsigned short* dst = &O[((size_t)e * HD + td + d) * HD + tk + kc];
        *reinterpret_cast<short8_t*>(dst) = u.v[0];
        *reinterpret_cast<short8_t*>(dst + 8) = u.v[1];
    }
}

// ---------------------------------------------------------------------------
// gating (unchanged, fp32 z): logits -> softmax -> top2 -> renorm
// ---------------------------------------------------------------------------
__global__ __launch_bounds__(256) void gate_kernel(
    const float* __restrict__ Z, const float* __restrict__ Wg,
    const float* __restrict__ bg, float* __restrict__ gate)
{
    const int lane = threadIdx.x & 63;
    const int n = blockIdx.x * 4 + (threadIdx.x >> 6);
    const float4 zv = *reinterpret_cast<const float4*>(&Z[(size_t)n * HD + lane * 4]);
    const float zz[4] = { zv.x, zv.y, zv.z, zv.w };
    float lg[8];
#pragma unroll
    for (int e = 0; e < 8; ++e) lg[e] = 0.f;
#pragma unroll
    for (int i = 0; i < 4; ++i) {
        const float* wr = &Wg[(size_t)(lane * 4 + i) * 8];
        const float4 w0 = *reinterpret_cast<const float4*>(wr);
        const float4 w1 = *reinterpret_cast<const float4*>(wr + 4);
        lg[0] = fmaf(zz[i], w0.x, lg[0]); lg[1] = fmaf(zz[i], w0.y, lg[1]);
        lg[2] = fmaf(zz[i], w0.z, lg[2]); lg[3] = fmaf(zz[i], w0.w, lg[3]);
        lg[4] = fmaf(zz[i], w1.x, lg[4]); lg[5] = fmaf(zz[i], w1.y, lg[5]);
        lg[6] = fmaf(zz[i], w1.z, lg[6]); lg[7] = fmaf(zz[i], w1.w, lg[7]);
    }
#pragma unroll
    for (int off = 32; off; off >>= 1)
#pragma unroll
        for (int e = 0; e < 8; ++e) lg[e] += __shfl_down(lg[e], off);

    if (lane == 0) {
        float m = -1e30f;
#pragma unroll
        for (int e = 0; e < 8; ++e) { lg[e] += bg[e]; m = fmaxf(m, lg[e]); }
        float p[8], s = 0.f;
#pragma unroll
        for (int e = 0; e < 8; ++e) { p[e] = expf(lg[e] - m); s += p[e]; }
        const float inv_s = 1.f / s;
#pragma unroll
        for (int e = 0; e < 8; ++e) p[e] *= inv_s;
        int e1 = 0;
#pragma unroll
        for (int e = 1; e < 8; ++e) if (p[e] > p[e1]) e1 = e;
        int e2 = (e1 == 0) ? 1 : 0;
#pragma unroll
        for (int e = 0; e < 8; ++e) if (e != e1 && p[e] > p[e2]) e2 = e;
        const float denom = 1.f / (p[e1] + p[e2] + 1e-8f);
        float g[8];
#pragma unroll
        for (int e = 0; e < 8; ++e) g[e] = 0.f;
        g[e1] = p[e1] * denom; g[e2] = p[e2] * denom;
        float* gr = &gate[(size_t)n * 8];
        *reinterpret_cast<float4*>(gr)     = make_float4(g[0], g[1], g[2], g[3]);
        *reinterpret_cast<float4*>(gr + 4) = make_float4(g[4], g[5], g[6], g[7]);
    }
}

// ---------------------------------------------------------------------------
// experts via MFMA: out[n,d] = sum_e g[n,e] * (Zb@Wt[e]^T + b[e,d])
// block tile 128(M) x 128(N), 4 waves each 64x64 (4x4 frags of 16x16x32)
// A (z) full-K resident in LDS; B streamed per (expert, k-step).
// LDS layout [k-chunk][row][8 bf16] -> ds_read_b128 frag fetch, ~2-way banks.
// ---------------------------------------------------------------------------
__global__ __launch_bounds__(256) void expert_mfma_kernel(
    const unsigned short* __restrict__ tzb, const unsigned short* __restrict__ izb,
    const unsigned short* __restrict__ wt_t, const unsigned short* __restrict__ wt_i,
    const float* __restrict__ bx_t, const float* __restrict__ bx_i,
    const float* __restrict__ g_t, const float* __restrict__ g_i,
    float* __restrict__ out_t, float* __restrict__ out_i)
{
    const int mod = blockIdx.z;
    const unsigned short* Zb = mod ? izb : tzb;
    const unsigned short* Wt = mod ? wt_i : wt_t;
    const float* bx   = mod ? bx_i : bx_t;
    const float* gate = mod ? g_i  : g_t;
    float* outp       = mod ? out_i : out_t;

    __shared__ unsigned short Al[32][128][8];  // 64 KB: full-K A tile
    __shared__ unsigned short Bl[4][128][8];   //  8 KB: one k-step of B
    __shared__ float gld[128][8];              //  4 KB: gate tile

    const int tid = threadIdx.x;
    const int lane = tid & 63;
    const int w = tid >> 6;
    const int wr = w >> 1, wc = w & 1;
    const int lg = lane >> 4;   // k-group / acc-row group
    const int lr = lane & 15;   // frag row (A) / col (B,D)
    const int m0 = blockIdx.x * 128;
    const int n0 = blockIdx.y * 128;

    // stage gate tile (coalesced float4)
    reinterpret_cast<float4*>(&gld[0][0])[tid] =
        reinterpret_cast<const float4*>(&gate[(size_t)m0 * 8])[tid];

    // stage A tile: 128 rows x 256 k (bf16)
    {
        const int r = tid >> 1, h = tid & 1;
        const unsigned short* src = &Zb[(size_t)(m0 + r) * HD + h * 128];
#pragma unroll
        for (int j = 0; j < 16; ++j)
            *reinterpret_cast<short8_t*>(&Al[h * 16 + j][r][0]) =
                *reinterpret_cast<const short8_t*>(&src[j * 8]);
    }
    __syncthreads();

    f32x4 accT[4][4];
#pragma unroll
    for (int mi = 0; mi < 4; ++mi)
#pragma unroll
        for (int ni = 0; ni < 4; ++ni)
            accT[mi][ni] = (f32x4){0.f, 0.f, 0.f, 0.f};

    for (int e = 0; e < 8; ++e) {
        f32x4 acc[4][4];
#pragma unroll
        for (int mi = 0; mi < 4; ++mi)
#pragma unroll
            for (int ni = 0; ni < 4; ++ni)
                acc[mi][ni] = (f32x4){0.f, 0.f, 0.f, 0.f};

        const unsigned short* We = &Wt[(size_t)e * HD * HD + (size_t)n0 * HD];

        for (int ks = 0; ks < 8; ++ks) {
            __syncthreads();
            {   // stage B k-step: 128 n-rows x 32 k
                const int n = tid >> 1, h = tid & 1;
                const unsigned short* s = &We[(size_t)n * HD + ks * 32 + h * 16];
                *reinterpret_cast<short8_t*>(&Bl[2 * h][n][0]) =
                    *reinterpret_cast<const short8_t*>(&s[0]);
                *reinterpret_cast<short8_t*>(&Bl[2 * h + 1][n][0]) =
                    *reinterpret_cast<const short8_t*>(&s[8]);
            }
            __syncthreads();

            short8_t af[4], bf[4];
#pragma unroll
            for (int mi = 0; mi < 4; ++mi)
                af[mi] = *reinterpret_cast<const short8_t*>(
                    &Al[ks * 4 + lg][wr * 64 + mi * 16 + lr][0]);
#pragma unroll
            for (int ni = 0; ni < 4; ++ni)
                bf[ni] = *reinterpret_cast<const short8_t*>(
                    &Bl[lg][wc * 64 + ni * 16 + lr][0]);
#pragma unroll
            for (int mi = 0; mi < 4; ++mi)
#pragma unroll
                for (int ni = 0; ni < 4; ++ni)
                    acc[mi][ni] = __builtin_amdgcn_mfma_f32_16x16x32_bf16(
                        af[mi], bf[ni], acc[mi][ni], 0, 0, 0);
        }

        // gate-weight + bias combine (fp32)
#pragma unroll
        for (int mi = 0; mi < 4; ++mi) {
            const int rb = wr * 64 + mi * 16 + lg * 4;
            const float gv0 = gld[rb + 0][e];
            const float gv1 = gld[rb + 1][e];
            const float gv2 = gld[rb + 2][e];
            const float gv3 = gld[rb + 3][e];
#pragma unroll
            for (int ni = 0; ni < 4; ++ni) {
                const float bv = bx[(size_t)e * HD + n0 + wc * 64 + ni * 16 + lr];
                accT[mi][ni][0] += gv0 * (acc[mi][ni][0] + bv);
                accT[mi][ni][1] += gv1 * (acc[mi][ni][1] + bv);
                accT[mi][ni][2] += gv2 * (acc[mi][ni][2] + bv);
                accT[mi][ni][3] += gv3 * (acc[mi][ni][3] + bv);
            }
        }
    }

#pragma unroll
    for (int mi = 0; mi < 4; ++mi)
#pragma unroll
        for (int ni = 0; ni < 4; ++ni)
#pragma unroll
            for (int r = 0; r < 4; ++r)
                outp[(size_t)(m0 + wr * 64 + mi * 16 + lg * 4 + r) * HD
                     + n0 + wc * 64 + ni * 16 + lr] = accT[mi][ni][r];
}

// ---------------------------------------------------------------------------
// fuse GEMM (fp32): fused_lin = [t_out | i_out] @ Wf + bf   (K = 512)
// ---------------------------------------------------------------------------
__global__ __launch_bounds__(256) void fusegemm_kernel(
    const float* __restrict__ t_out, const float* __restrict__ i_out,
    const float* __restrict__ Wf, const float* __restrict__ bf,
    float* __restrict__ fused)
{
    __shared__ float As[32][68];
    __shared__ float Ws[32][68];
    const int n0 = blockIdx.x * 64;
    const int d0 = blockIdx.y * 64;
    const int tid = threadIdx.x;
    const int tx = tid & 15, ty = tid >> 4;
    float acc[4][4] = {};

    for (int k0 = 0; k0 < 2 * HD; k0 += 32) {
        const float* Abuf = (k0 < HD) ? t_out : i_out;
        const int kloc = k0 & (HD - 1);
        __syncthreads();
#pragma unroll
        for (int p = 0; p < 2; ++p) {
            const int r = (tid >> 3) + p * 32;
            const int c = (tid & 7) * 4;
            const float4 v = *reinterpret_cast<const float4*>(
                &Abuf[(size_t)(n0 + r) * HD + kloc + c]);
            As[c + 0][r] = v.x; As[c + 1][r] = v.y;
            As[c + 2][r] = v.z; As[c + 3][r] = v.w;
        }
#pragma unroll
        for (int p = 0; p < 2; ++p) {
            const int r = (tid >> 4) + p * 16;
            const int c = (tid & 15) * 4;
            *reinterpret_cast<float4*>(&Ws[r][c]) =
                *reinterpret_cast<const float4*>(&Wf[(size_t)(k0 + r) * HD + d0 + c]);
        }
        __syncthreads();
#pragma unroll
        for (int kk = 0; kk < 32; ++kk) {
            float a[4], w[4];
#pragma unroll
            for (int i = 0; i < 4; ++i) a[i] = As[kk][ty * 4 + i];
#pragma unroll
            for (int j = 0; j < 4; ++j) w[j] = Ws[kk][tx * 4 + j];
#pragma unroll
            for (int i = 0; i < 4; ++i)
#pragma unroll
                for (int j = 0; j < 4; ++j)
                    acc[i][j] = fmaf(a[i], w[j], acc[i][j]);
        }
    }
#pragma unroll
    for (int i = 0; i < 4; ++i) {
        const int n = n0 + ty * 4 + i;
#pragma unroll
        for (int j = 0; j < 4; ++j) {
            const int d = d0 + tx * 4 + j;
            fused[(size_t)n * HD + d] = acc[i][j] + bf[d];
        }
    }
}

// ---------------------------------------------------------------------------
// LN -> ReLU -> +item
// ---------------------------------------------------------------------------
__global__ __launch_bounds__(256) void ln_relu_res_kernel(
    const float* __restrict__ fused, const float* __restrict__ g,
    const float* __restrict__ b, const float* __restrict__ item,
    float* __restrict__ fusion)
{
    const int lane = threadIdx.x & 63;
    const int n = blockIdx.x * 4 + (threadIdx.x >> 6);
    const size_t off = (size_t)n * HD + lane * 4;
    const float4 x = *reinterpret_cast<const float4*>(&fused[off]);
    float s = x.x + x.y + x.z + x.w;
    float ss = x.x * x.x + x.y * x.y + x.z * x.z + x.w * x.w;
#pragma unroll
    for (int o = 32; o; o >>= 1) { s += __shfl_xor(s, o); ss += __shfl_xor(ss, o); }
    const float mean = s * (1.f / 256.f);
    const float var = ss * (1.f / 256.f) - mean * mean;
    const float rstd = rsqrtf(var + 1e-5f);
    const float4 gg = *reinterpret_cast<const float4*>(&g[lane * 4]);
    const float4 bb = *reinterpret_cast<const float4*>(&b[lane * 4]);
    const float4 it = *reinterpret_cast<const float4*>(&item[off]);
    float4 o4;
    o4.x = fmaxf((x.x - mean) * rstd * gg.x + bb.x, 0.f) + it.x;
    o4.y = fmaxf((x.y - mean) * rstd * gg.y + bb.y, 0.f) + it.y;
    o4.z = fmaxf((x.z - mean) * rstd * gg.z + bb.z, 0.f) + it.z;
    o4.w = fmaxf((x.w - mean) * rstd * gg.w + bb.w, 0.f) + it.w;
    *reinterpret_cast<float4*>(&fusion[off]) = o4;
}

// ---------------------------------------------------------------------------
extern "C" void kernel_launch(void* const* d_in, const int* in_sizes, int n_in,
                              void* d_out, int out_size, void* d_ws, size_t ws_size,
                              hipStream_t stream)
{
    const float* text    = (const float*)d_in[0];
    const float* img     = (const float*)d_in[1];
    const float* item    = (const float*)d_in[2];
    const float* noise_t = (const float*)d_in[3];
    const float* noise_i = (const float*)d_in[4];
    const float* W_mu_t  = (const float*)d_in[5];
    const float* b_mu_t  = (const float*)d_in[6];
    const float* W_sg_t  = (const float*)d_in[7];
    const float* b_sg_t  = (const float*)d_in[8];
    const float* W_mu_i  = (const float*)d_in[9];
    const float* b_mu_i  = (const float*)d_in[10];
    const float* W_sg_i  = (const float*)d_in[11];
    const float* b_sg_i  = (const float*)d_in[12];
    const float* W_gate  = (const float*)d_in[13];
    const float* b_gate  = (const float*)d_in[14];
    const float* W_texp  = (const float*)d_in[15];
    const float* b_texp  = (const float*)d_in[16];
    const float* W_iexp  = (const float*)d_in[17];
    const float* b_iexp  = (const float*)d_in[18];
    const float* W_fuse  = (const float*)d_in[19];
    const float* b_fuse  = (const float*)d_in[20];
    const float* ln_g    = (const float*)d_in[21];
    const float* ln_b    = (const float*)d_in[22];

    float* out    = (float*)d_out;
    float* fusion = out;
    float* o_tmu  = out + (size_t)SOUT;
    float* o_tsig = out + (size_t)2 * SOUT;
    float* o_imu  = out + (size_t)3 * SOUT;
    float* o_isig = out + (size_t)4 * SOUT;

    // ws layout
    float* ws      = (float*)d_ws;
    float* t_z     = ws;                       // SOUT fp32, reused as t_out
    float* i_z     = ws + (size_t)SOUT;        // SOUT fp32, reused as i_out
    float* fused   = ws + (size_t)2 * SOUT;    // SOUT fp32
    float* t_gate  = ws + (size_t)3 * SOUT;    // NTOK*8
    float* i_gate  = t_gate + (size_t)NTOK * 8;
    unsigned short* tzb  = (unsigned short*)(i_gate + (size_t)NTOK * 8);  // SOUT bf16
    unsigned short* izb  = tzb + (size_t)SOUT;
    unsigned short* wt_t = izb + (size_t)SOUT;          // 8*256*256 bf16
    unsigned short* wt_i = wt_t + (size_t)8 * HD * HD;

    float* t_out = t_z;
    float* i_out = i_z;

    // W transpose+convert (independent of data path)
    transposeW_kernel<<<dim3(16, 8, 2), 256, 0, stream>>>(W_texp, W_iexp, wt_t, wt_i);

    const dim3 gemm_grid(NTOK / 64, HD / 64);  // 200 x 4
    reparam_kernel<<<gemm_grid, 256, 0, stream>>>(
        text, W_mu_t, b_mu_t, W_sg_t, b_sg_t, noise_t, o_tmu, o_tsig, t_z, tzb);
    reparam_kernel<<<gemm_grid, 256, 0, stream>>>(
        img, W_mu_i, b_mu_i, W_sg_i, b_sg_i, noise_i, o_imu, o_isig, i_z, izb);

    gate_kernel<<<NTOK / 4, 256, 0, stream>>>(t_z, W_gate, b_gate, t_gate);
    gate_kernel<<<NTOK / 4, 256, 0, stream>>>(i_z, W_gate, b_gate, i_gate);

    // both modalities in one launch: grid 100 x 2 x 2
    expert_mfma_kernel<<<dim3(NTOK / 128, 2, 2), 256, 0, stream>>>(
        tzb, izb, wt_t, wt_i, b_texp, b_iexp, t_gate, i_gate, t_out, i_out);

    fusegemm_kernel<<<gemm_grid, 256, 0, stream>>>(t_out, i_out, W_fuse, b_fuse, fused);

    ln_relu_res_kernel<<<NTOK / 4, 256, 0, stream>>>(fused, ln_g, ln_b, item, fusion);
}

// Round 4
// 165.645 us; speedup vs baseline: 4.0177x; 1.5348x over previous
//
#include <hip/hip_runtime.h>
#include <hip/hip_bf16.h>
#include <math.h>

#define NTOK 12800
#define HD 256
#define SOUT (NTOK * HD)

typedef __attribute__((ext_vector_type(8))) short short8_t;
typedef __attribute__((ext_vector_type(4))) float f32x4;

__device__ __forceinline__ unsigned short f2b(float f) {
    union { float f; unsigned u; } v; v.f = f;
    unsigned r = (v.u + 0x7FFFu + ((v.u >> 16) & 1u)) >> 16;
    return (unsigned short)r;
}
__device__ __forceinline__ float b2f(unsigned short s) {
    union { unsigned u; float f; } v; v.u = ((unsigned)s) << 16;
    return v.f;
}

// ---------------------------------------------------------------------------
// prepW: transpose+convert weights fp32 [k][d] -> bf16 [d][k].
// For the 4 reparam weights also emit the bf16 residual (lo part) for
// split-precision MFMA.
// z: 0..7 W_texp, 8..15 W_iexp, 16..19 reparam (hi+lo), 20..21 W_fuse halves
// ---------------------------------------------------------------------------
__global__ __launch_bounds__(256) void prepW_kernel(
    const float* __restrict__ W_texp, const float* __restrict__ W_iexp,
    const float* __restrict__ W_mu_t, const float* __restrict__ W_sg_t,
    const float* __restrict__ W_mu_i, const float* __restrict__ W_sg_i,
    const float* __restrict__ W_fuse,
    unsigned short* __restrict__ wt_t, unsigned short* __restrict__ wt_i,
    unsigned short* __restrict__ wt_f,
    unsigned short* __restrict__ wt_muth, unsigned short* __restrict__ wt_mutl,
    unsigned short* __restrict__ wt_sgth, unsigned short* __restrict__ wt_sgtl,
    unsigned short* __restrict__ wt_muih, unsigned short* __restrict__ wt_muil,
    unsigned short* __restrict__ wt_sgih, unsigned short* __restrict__ wt_sgil)
{
    const int z = blockIdx.y;
    const float* src;
    unsigned short* dsth;
    unsigned short* dstl = nullptr;
    int dstride = 256, koff = 0;
    if (z < 8)       { src = W_texp + (size_t)z * 65536;       dsth = wt_t + (size_t)z * 65536; }
    else if (z < 16) { src = W_iexp + (size_t)(z - 8) * 65536; dsth = wt_i + (size_t)(z - 8) * 65536; }
    else if (z == 16){ src = W_mu_t; dsth = wt_muth; dstl = wt_mutl; }
    else if (z == 17){ src = W_sg_t; dsth = wt_sgth; dstl = wt_sgtl; }
    else if (z == 18){ src = W_mu_i; dsth = wt_muih; dstl = wt_muil; }
    else if (z == 19){ src = W_sg_i; dsth = wt_sgih; dstl = wt_sgil; }
    else if (z == 20){ src = W_fuse;         dsth = wt_f; dstride = 512; koff = 0;   }
    else             { src = W_fuse + 65536; dsth = wt_f; dstride = 512; koff = 256; }

    const int tk = (blockIdx.x >> 2) * 64;
    const int td = (blockIdx.x & 3) * 64;
    __shared__ float T[64][68];
    const int t = threadIdx.x;
    {
        const int r = t >> 2, c0 = (t & 3) * 16;
        const float* s = &src[(size_t)(tk + r) * 256 + td + c0];
#pragma unroll
        for (int j = 0; j < 4; ++j)
            *reinterpret_cast<float4*>(&T[r][c0 + j * 4]) =
                *reinterpret_cast<const float4*>(&s[j * 4]);
    }
    __syncthreads();
    {
        const int d = t & 63, kc = (t >> 6) * 16;
        union { unsigned short s[16]; short8_t v[2]; } uh, ul;
#pragma unroll
        for (int j = 0; j < 16; ++j) {
            const float x = T[kc + j][d];
            uh.s[j] = f2b(x);
            ul.s[j] = f2b(x - b2f(uh.s[j]));
        }
        unsigned short* p = &dsth[(size_t)(td + d) * dstride + koff + tk + kc];
        *reinterpret_cast<short8_t*>(p) = uh.v[0];
        *reinterpret_cast<short8_t*>(p + 8) = uh.v[1];
        if (dstl) {
            unsigned short* q = &dstl[(size_t)(td + d) * 256 + tk + kc];
            *reinterpret_cast<short8_t*>(q) = ul.v[0];
            *reinterpret_cast<short8_t*>(q + 8) = ul.v[1];
        }
    }
}

// ---------------------------------------------------------------------------
// reparam via split-precision MFMA (3-pass: Ah*Wh + Ah*Wl + Al*Wh):
// mu = A@Wmu + bmu ; sig = exp(A@Wsg + bsg)  -- fp32-grade accuracy
// z = mu + sig*noise emitted bf16 for experts; gate recomputes z from mu/sig.
// tile 128(M) x 128(N), BK=32, both weight streams share the A tile.
// ---------------------------------------------------------------------------
__global__ __launch_bounds__(256) void reparam_mfma_kernel(
    const float* __restrict__ text, const float* __restrict__ img,
    const unsigned short* __restrict__ wt_muth, const unsigned short* __restrict__ wt_mutl,
    const unsigned short* __restrict__ wt_sgth, const unsigned short* __restrict__ wt_sgtl,
    const unsigned short* __restrict__ wt_muih, const unsigned short* __restrict__ wt_muil,
    const unsigned short* __restrict__ wt_sgih, const unsigned short* __restrict__ wt_sgil,
    const float* __restrict__ b_mu_t, const float* __restrict__ b_sg_t,
    const float* __restrict__ b_mu_i, const float* __restrict__ b_sg_i,
    const float* __restrict__ noise_t, const float* __restrict__ noise_i,
    float* __restrict__ o_tmu, float* __restrict__ o_tsig,
    float* __restrict__ o_imu, float* __restrict__ o_isig,
    unsigned short* __restrict__ tzb, unsigned short* __restrict__ izb)
{
    const int mod = blockIdx.z;
    const float* A            = mod ? img     : text;
    const unsigned short* Wmh = mod ? wt_muih : wt_muth;
    const unsigned short* Wml = mod ? wt_muil : wt_mutl;
    const unsigned short* Wsh = mod ? wt_sgih : wt_sgth;
    const unsigned short* Wsl = mod ? wt_sgil : wt_sgtl;
    const float* bmu          = mod ? b_mu_i  : b_mu_t;
    const float* bsg          = mod ? b_sg_i  : b_sg_t;
    const float* noise        = mod ? noise_i : noise_t;
    float* omu                = mod ? o_imu   : o_tmu;
    float* osg                = mod ? o_isig  : o_tsig;
    unsigned short* zb        = mod ? izb     : tzb;

    __shared__ __align__(16) unsigned short Ahs[4][128][8];   // 8 KB each
    __shared__ __align__(16) unsigned short Als[4][128][8];
    __shared__ __align__(16) unsigned short BMh[4][128][8];
    __shared__ __align__(16) unsigned short BMl[4][128][8];
    __shared__ __align__(16) unsigned short BSh[4][128][8];
    __shared__ __align__(16) unsigned short BSl[4][128][8];   // total 48 KB

    const int tid = threadIdx.x;
    const int lane = tid & 63;
    const int w = tid >> 6;
    const int wr = w >> 1, wc = w & 1;
    const int lg = lane >> 4;
    const int lr = lane & 15;
    const int m0 = blockIdx.x * 128;
    const int n0 = blockIdx.y * 128;

    f32x4 accM[4][4], accS[4][4];
#pragma unroll
    for (int mi = 0; mi < 4; ++mi)
#pragma unroll
        for (int ni = 0; ni < 4; ++ni) {
            accM[mi][ni] = (f32x4){0.f, 0.f, 0.f, 0.f};
            accS[mi][ni] = (f32x4){0.f, 0.f, 0.f, 0.f};
        }

    for (int ks = 0; ks < 8; ++ks) {
        __syncthreads();
        {   // stage A hi/lo: 128 rows x 32 k (fp32 -> bf16 hi + residual lo)
            const int r = tid >> 1, h = tid & 1;
            const float* s = &A[(size_t)(m0 + r) * HD + ks * 32 + h * 16];
#pragma unroll
            for (int j = 0; j < 2; ++j) {
                const float4 v0 = *reinterpret_cast<const float4*>(&s[j * 8]);
                const float4 v1 = *reinterpret_cast<const float4*>(&s[j * 8 + 4]);
                float x[8] = { v0.x, v0.y, v0.z, v0.w, v1.x, v1.y, v1.z, v1.w };
                union { unsigned short u[8]; short8_t v; } qh, ql;
#pragma unroll
                for (int c = 0; c < 8; ++c) {
                    qh.u[c] = f2b(x[c]);
                    ql.u[c] = f2b(x[c] - b2f(qh.u[c]));
                }
                *reinterpret_cast<short8_t*>(&Ahs[h * 2 + j][r][0]) = qh.v;
                *reinterpret_cast<short8_t*>(&Als[h * 2 + j][r][0]) = ql.v;
            }
        }
        {   // stage B: 4 streams x 128 n-rows x 32 k
            const int n = tid >> 1, h = tid & 1;
            const size_t wo = (size_t)(n0 + n) * HD + ks * 32 + h * 16;
#pragma unroll
            for (int j = 0; j < 2; ++j) {
                *reinterpret_cast<short8_t*>(&BMh[2 * h + j][n][0]) =
                    *reinterpret_cast<const short8_t*>(&Wmh[wo + j * 8]);
                *reinterpret_cast<short8_t*>(&BMl[2 * h + j][n][0]) =
                    *reinterpret_cast<const short8_t*>(&Wml[wo + j * 8]);
                *reinterpret_cast<short8_t*>(&BSh[2 * h + j][n][0]) =
                    *reinterpret_cast<const short8_t*>(&Wsh[wo + j * 8]);
                *reinterpret_cast<short8_t*>(&BSl[2 * h + j][n][0]) =
                    *reinterpret_cast<const short8_t*>(&Wsl[wo + j * 8]);
            }
        }
        __syncthreads();

        short8_t ahf[4], alf[4];
#pragma unroll
        for (int mi = 0; mi < 4; ++mi) {
            ahf[mi] = *reinterpret_cast<const short8_t*>(&Ahs[lg][wr * 64 + mi * 16 + lr][0]);
            alf[mi] = *reinterpret_cast<const short8_t*>(&Als[lg][wr * 64 + mi * 16 + lr][0]);
        }
#pragma unroll
        for (int ni = 0; ni < 4; ++ni) {
            const short8_t bmh = *reinterpret_cast<const short8_t*>(&BMh[lg][wc * 64 + ni * 16 + lr][0]);
            const short8_t bml = *reinterpret_cast<const short8_t*>(&BMl[lg][wc * 64 + ni * 16 + lr][0]);
            const short8_t bsh = *reinterpret_cast<const short8_t*>(&BSh[lg][wc * 64 + ni * 16 + lr][0]);
            const short8_t bsl = *reinterpret_cast<const short8_t*>(&BSl[lg][wc * 64 + ni * 16 + lr][0]);
#pragma unroll
            for (int mi = 0; mi < 4; ++mi) {
                accM[mi][ni] = __builtin_amdgcn_mfma_f32_16x16x32_bf16(ahf[mi], bmh, accM[mi][ni], 0, 0, 0);
                accM[mi][ni] = __builtin_amdgcn_mfma_f32_16x16x32_bf16(ahf[mi], bml, accM[mi][ni], 0, 0, 0);
                accM[mi][ni] = __builtin_amdgcn_mfma_f32_16x16x32_bf16(alf[mi], bmh, accM[mi][ni], 0, 0, 0);
                accS[mi][ni] = __builtin_amdgcn_mfma_f32_16x16x32_bf16(ahf[mi], bsh, accS[mi][ni], 0, 0, 0);
                accS[mi][ni] = __builtin_amdgcn_mfma_f32_16x16x32_bf16(ahf[mi], bsl, accS[mi][ni], 0, 0, 0);
                accS[mi][ni] = __builtin_amdgcn_mfma_f32_16x16x32_bf16(alf[mi], bsh, accS[mi][ni], 0, 0, 0);
            }
        }
    }

    // epilogue: bias, exp, reparameterize
    float bm[4], bs[4];
    int cc[4];
#pragma unroll
    for (int ni = 0; ni < 4; ++ni) {
        cc[ni] = n0 + wc * 64 + ni * 16 + lr;
        bm[ni] = bmu[cc[ni]];
        bs[ni] = bsg[cc[ni]];
    }
#pragma unroll
    for (int mi = 0; mi < 4; ++mi) {
#pragma unroll
        for (int r = 0; r < 4; ++r) {
            const int row = m0 + wr * 64 + mi * 16 + lg * 4 + r;
#pragma unroll
            for (int ni = 0; ni < 4; ++ni) {
                const size_t off = (size_t)row * HD + cc[ni];
                const float mu = accM[mi][ni][r] + bm[ni];
                const float sg = expf(accS[mi][ni][r] + bs[ni]);
                omu[off] = mu;
                osg[off] = sg;
                zb[off] = f2b(fmaf(sg, noise[off], mu));
            }
        }
    }
}

// ---------------------------------------------------------------------------
// gating from fp32 mu/sig/noise (z recomputed exactly as epilogue):
// logits -> softmax -> top2 -> renorm
// ---------------------------------------------------------------------------
__global__ __launch_bounds__(256) void gate_kernel(
    const float* __restrict__ mu, const float* __restrict__ sig,
    const float* __restrict__ noise, const float* __restrict__ Wg,
    const float* __restrict__ bg, float* __restrict__ gate)
{
    const int lane = threadIdx.x & 63;
    const int n = blockIdx.x * 4 + (threadIdx.x >> 6);
    const size_t off = (size_t)n * HD + lane * 4;
    const float4 m4 = *reinterpret_cast<const float4*>(&mu[off]);
    const float4 s4 = *reinterpret_cast<const float4*>(&sig[off]);
    const float4 n4 = *reinterpret_cast<const float4*>(&noise[off]);
    const float zz[4] = { fmaf(s4.x, n4.x, m4.x), fmaf(s4.y, n4.y, m4.y),
                          fmaf(s4.z, n4.z, m4.z), fmaf(s4.w, n4.w, m4.w) };
    float lg[8];
#pragma unroll
    for (int e = 0; e < 8; ++e) lg[e] = 0.f;
#pragma unroll
    for (int i = 0; i < 4; ++i) {
        const float* wr = &Wg[(size_t)(lane * 4 + i) * 8];
        const float4 w0 = *reinterpret_cast<const float4*>(wr);
        const float4 w1 = *reinterpret_cast<const float4*>(wr + 4);
        lg[0] = fmaf(zz[i], w0.x, lg[0]); lg[1] = fmaf(zz[i], w0.y, lg[1]);
        lg[2] = fmaf(zz[i], w0.z, lg[2]); lg[3] = fmaf(zz[i], w0.w, lg[3]);
        lg[4] = fmaf(zz[i], w1.x, lg[4]); lg[5] = fmaf(zz[i], w1.y, lg[5]);
        lg[6] = fmaf(zz[i], w1.z, lg[6]); lg[7] = fmaf(zz[i], w1.w, lg[7]);
    }
#pragma unroll
    for (int off2 = 32; off2; off2 >>= 1)
#pragma unroll
        for (int e = 0; e < 8; ++e) lg[e] += __shfl_down(lg[e], off2);

    if (lane == 0) {
        float m = -1e30f;
#pragma unroll
        for (int e = 0; e < 8; ++e) { lg[e] += bg[e]; m = fmaxf(m, lg[e]); }
        float p[8], s = 0.f;
#pragma unroll
        for (int e = 0; e < 8; ++e) { p[e] = expf(lg[e] - m); s += p[e]; }
        const float inv_s = 1.f / s;
#pragma unroll
        for (int e = 0; e < 8; ++e) p[e] *= inv_s;
        int e1 = 0;
#pragma unroll
        for (int e = 1; e < 8; ++e) if (p[e] > p[e1]) e1 = e;
        int e2 = (e1 == 0) ? 1 : 0;
#pragma unroll
        for (int e = 0; e < 8; ++e) if (e != e1 && p[e] > p[e2]) e2 = e;
        const float denom = 1.f / (p[e1] + p[e2] + 1e-8f);
        float g[8];
#pragma unroll
        for (int e = 0; e < 8; ++e) g[e] = 0.f;
        g[e1] = p[e1] * denom; g[e2] = p[e2] * denom;
        float* gr = &gate[(size_t)n * 8];
        *reinterpret_cast<float4*>(gr)     = make_float4(g[0], g[1], g[2], g[3]);
        *reinterpret_cast<float4*>(gr + 4) = make_float4(g[4], g[5], g[6], g[7]);
    }
}

// ---------------------------------------------------------------------------
// experts via MFMA, bf16 output for the fuse GEMM
// ---------------------------------------------------------------------------
__global__ __launch_bounds__(256) void expert_mfma_kernel(
    const unsigned short* __restrict__ tzb, const unsigned short* __restrict__ izb,
    const unsigned short* __restrict__ wt_t, const unsigned short* __restrict__ wt_i,
    const float* __restrict__ bx_t, const float* __restrict__ bx_i,
    const float* __restrict__ g_t, const float* __restrict__ g_i,
    unsigned short* __restrict__ out_t, unsigned short* __restrict__ out_i)
{
    const int mod = blockIdx.z;
    const unsigned short* Zb = mod ? izb : tzb;
    const unsigned short* Wt = mod ? wt_i : wt_t;
    const float* bx   = mod ? bx_i : bx_t;
    const float* gate = mod ? g_i  : g_t;
    unsigned short* outp = mod ? out_i : out_t;

    __shared__ __align__(16) unsigned short Al[32][128][8];  // 64 KB
    __shared__ __align__(16) unsigned short Bl[4][128][8];   //  8 KB
    __shared__ float gld[128][8];                            //  4 KB

    const int tid = threadIdx.x;
    const int lane = tid & 63;
    const int w = tid >> 6;
    const int wr = w >> 1, wc = w & 1;
    const int lg = lane >> 4;
    const int lr = lane & 15;
    const int m0 = blockIdx.x * 128;
    const int n0 = blockIdx.y * 128;

    reinterpret_cast<float4*>(&gld[0][0])[tid] =
        reinterpret_cast<const float4*>(&gate[(size_t)m0 * 8])[tid];

    {
        const int r = tid >> 1, h = tid & 1;
        const unsigned short* src = &Zb[(size_t)(m0 + r) * HD + h * 128];
#pragma unroll
        for (int j = 0; j < 16; ++j)
            *reinterpret_cast<short8_t*>(&Al[h * 16 + j][r][0]) =
                *reinterpret_cast<const short8_t*>(&src[j * 8]);
    }
    __syncthreads();

    f32x4 accT[4][4];
#pragma unroll
    for (int mi = 0; mi < 4; ++mi)
#pragma unroll
        for (int ni = 0; ni < 4; ++ni)
            accT[mi][ni] = (f32x4){0.f, 0.f, 0.f, 0.f};

    for (int e = 0; e < 8; ++e) {
        f32x4 acc[4][4];
#pragma unroll
        for (int mi = 0; mi < 4; ++mi)
#pragma unroll
            for (int ni = 0; ni < 4; ++ni)
                acc[mi][ni] = (f32x4){0.f, 0.f, 0.f, 0.f};

        const unsigned short* We = &Wt[(size_t)e * HD * HD + (size_t)n0 * HD];

        for (int ks = 0; ks < 8; ++ks) {
            __syncthreads();
            {
                const int n = tid >> 1, h = tid & 1;
                const unsigned short* s = &We[(size_t)n * HD + ks * 32 + h * 16];
                *reinterpret_cast<short8_t*>(&Bl[2 * h][n][0]) =
                    *reinterpret_cast<const short8_t*>(&s[0]);
                *reinterpret_cast<short8_t*>(&Bl[2 * h + 1][n][0]) =
                    *reinterpret_cast<const short8_t*>(&s[8]);
            }
            __syncthreads();

            short8_t af[4], bf[4];
#pragma unroll
            for (int mi = 0; mi < 4; ++mi)
                af[mi] = *reinterpret_cast<const short8_t*>(
                    &Al[ks * 4 + lg][wr * 64 + mi * 16 + lr][0]);
#pragma unroll
            for (int ni = 0; ni < 4; ++ni)
                bf[ni] = *reinterpret_cast<const short8_t*>(
                    &Bl[lg][wc * 64 + ni * 16 + lr][0]);
#pragma unroll
            for (int mi = 0; mi < 4; ++mi)
#pragma unroll
                for (int ni = 0; ni < 4; ++ni)
                    acc[mi][ni] = __builtin_amdgcn_mfma_f32_16x16x32_bf16(
                        af[mi], bf[ni], acc[mi][ni], 0, 0, 0);
        }

#pragma unroll
        for (int mi = 0; mi < 4; ++mi) {
            const int rb = wr * 64 + mi * 16 + lg * 4;
            const float gv0 = gld[rb + 0][e];
            const float gv1 = gld[rb + 1][e];
            const float gv2 = gld[rb + 2][e];
            const float gv3 = gld[rb + 3][e];
#pragma unroll
            for (int ni = 0; ni < 4; ++ni) {
                const float bv = bx[(size_t)e * HD + n0 + wc * 64 + ni * 16 + lr];
                accT[mi][ni][0] += gv0 * (acc[mi][ni][0] + bv);
                accT[mi][ni][1] += gv1 * (acc[mi][ni][1] + bv);
                accT[mi][ni][2] += gv2 * (acc[mi][ni][2] + bv);
                accT[mi][ni][3] += gv3 * (acc[mi][ni][3] + bv);
            }
        }
    }

#pragma unroll
    for (int mi = 0; mi < 4; ++mi)
#pragma unroll
        for (int ni = 0; ni < 4; ++ni)
#pragma unroll
            for (int r = 0; r < 4; ++r)
                outp[(size_t)(m0 + wr * 64 + mi * 16 + lg * 4 + r) * HD
                     + n0 + wc * 64 + ni * 16 + lr] = f2b(accT[mi][ni][r]);
}

// ---------------------------------------------------------------------------
// fuse GEMM via MFMA: fused = [t_out | i_out](bf16) @ WfT + bf   (K = 512)
// ---------------------------------------------------------------------------
__global__ __launch_bounds__(256) void fusegemm_mfma_kernel(
    const unsigned short* __restrict__ t_outb, const unsigned short* __restrict__ i_outb,
    const unsigned short* __restrict__ wtf, const float* __restrict__ bfuse,
    float* __restrict__ fused)
{
    __shared__ __align__(16) unsigned short Al[8][128][8];  // 16 KB
    __shared__ __align__(16) unsigned short Bl[8][128][8];  // 16 KB

    const int tid = threadIdx.x;
    const int lane = tid & 63;
    const int w = tid >> 6;
    const int wr = w >> 1, wc = w & 1;
    const int lg = lane >> 4;
    const int lr = lane & 15;
    const int m0 = blockIdx.x * 128;
    const int n0 = blockIdx.y * 128;

    f32x4 acc[4][4];
#pragma unroll
    for (int mi = 0; mi < 4; ++mi)
#pragma unroll
        for (int ni = 0; ni < 4; ++ni)
            acc[mi][ni] = (f32x4){0.f, 0.f, 0.f, 0.f};

    for (int ks = 0; ks < 8; ++ks) {  // K=512, 64 per step
        __syncthreads();
        {
            const int r = tid >> 1, h = tid & 1;
            const unsigned short* base = (ks < 4) ? t_outb : i_outb;
            const int kloc = (ks & 3) * 64 + h * 32;
            const unsigned short* s = &base[(size_t)(m0 + r) * HD + kloc];
#pragma unroll
            for (int j = 0; j < 4; ++j)
                *reinterpret_cast<short8_t*>(&Al[h * 4 + j][r][0]) =
                    *reinterpret_cast<const short8_t*>(&s[j * 8]);
        }
        {
            const int n = tid >> 1, h = tid & 1;
            const unsigned short* s = &wtf[(size_t)(n0 + n) * 512 + ks * 64 + h * 32];
#pragma unroll
            for (int j = 0; j < 4; ++j)
                *reinterpret_cast<short8_t*>(&Bl[h * 4 + j][n][0]) =
                    *reinterpret_cast<const short8_t*>(&s[j * 8]);
        }
        __syncthreads();

#pragma unroll
        for (int kc = 0; kc < 2; ++kc) {
            short8_t af[4], bf[4];
#pragma unroll
            for (int mi = 0; mi < 4; ++mi)
                af[mi] = *reinterpret_cast<const short8_t*>(
                    &Al[kc * 4 + lg][wr * 64 + mi * 16 + lr][0]);
#pragma unroll
            for (int ni = 0; ni < 4; ++ni)
                bf[ni] = *reinterpret_cast<const short8_t*>(
                    &Bl[kc * 4 + lg][wc * 64 + ni * 16 + lr][0]);
#pragma unroll
            for (int mi = 0; mi < 4; ++mi)
#pragma unroll
                for (int ni = 0; ni < 4; ++ni)
                    acc[mi][ni] = __builtin_amdgcn_mfma_f32_16x16x32_bf16(
                        af[mi], bf[ni], acc[mi][ni], 0, 0, 0);
        }
    }

    float bv[4];
    int cc[4];
#pragma unroll
    for (int ni = 0; ni < 4; ++ni) {
        cc[ni] = n0 + wc * 64 + ni * 16 + lr;
        bv[ni] = bfuse[cc[ni]];
    }
#pragma unroll
    for (int mi = 0; mi < 4; ++mi)
#pragma unroll
        for (int r = 0; r < 4; ++r) {
            const int row = m0 + wr * 64 + mi * 16 + lg * 4 + r;
#pragma unroll
            for (int ni = 0; ni < 4; ++ni)
                fused[(size_t)row * HD + cc[ni]] = acc[mi][ni][r] + bv[ni];
        }
}

// ---------------------------------------------------------------------------
// LN -> ReLU -> +item
// ---------------------------------------------------------------------------
__global__ __launch_bounds__(256) void ln_relu_res_kernel(
    const float* __restrict__ fused, const float* __restrict__ g,
    const float* __restrict__ b, const float* __restrict__ item,
    float* __restrict__ fusion)
{
    const int lane = threadIdx.x & 63;
    const int n = blockIdx.x * 4 + (threadIdx.x >> 6);
    const size_t off = (size_t)n * HD + lane * 4;
    const float4 x = *reinterpret_cast<const float4*>(&fused[off]);
    float s = x.x + x.y + x.z + x.w;
    float ss = x.x * x.x + x.y * x.y + x.z * x.z + x.w * x.w;
#pragma unroll
    for (int o = 32; o; o >>= 1) { s += __shfl_xor(s, o); ss += __shfl_xor(ss, o); }
    const float mean = s * (1.f / 256.f);
    const float var = ss * (1.f / 256.f) - mean * mean;
    const float rstd = rsqrtf(var + 1e-5f);
    const float4 gg = *reinterpret_cast<const float4*>(&g[lane * 4]);
    const float4 bb = *reinterpret_cast<const float4*>(&b[lane * 4]);
    const float4 it = *reinterpret_cast<const float4*>(&item[off]);
    float4 o4;
    o4.x = fmaxf((x.x - mean) * rstd * gg.x + bb.x, 0.f) + it.x;
    o4.y = fmaxf((x.y - mean) * rstd * gg.y + bb.y, 0.f) + it.y;
    o4.z = fmaxf((x.z - mean) * rstd * gg.z + bb.z, 0.f) + it.z;
    o4.w = fmaxf((x.w - mean) * rstd * gg.w + bb.w, 0.f) + it.w;
    *reinterpret_cast<float4*>(&fusion[off]) = o4;
}

// ---------------------------------------------------------------------------
extern "C" void kernel_launch(void* const* d_in, const int* in_sizes, int n_in,
                              void* d_out, int out_size, void* d_ws, size_t ws_size,
                              hipStream_t stream)
{
    const float* text    = (const float*)d_in[0];
    const float* img     = (const float*)d_in[1];
    const float* item    = (const float*)d_in[2];
    const float* noise_t = (const float*)d_in[3];
    const float* noise_i = (const float*)d_in[4];
    const float* W_mu_t  = (const float*)d_in[5];
    const float* b_mu_t  = (const float*)d_in[6];
    const float* W_sg_t  = (const float*)d_in[7];
    const float* b_sg_t  = (const float*)d_in[8];
    const float* W_mu_i  = (const float*)d_in[9];
    const float* b_mu_i  = (const float*)d_in[10];
    const float* W_sg_i  = (const float*)d_in[11];
    const float* b_sg_i  = (const float*)d_in[12];
    const float* W_gate  = (const float*)d_in[13];
    const float* b_gate  = (const float*)d_in[14];
    const float* W_texp  = (const float*)d_in[15];
    const float* b_texp  = (const float*)d_in[16];
    const float* W_iexp  = (const float*)d_in[17];
    const float* b_iexp  = (const float*)d_in[18];
    const float* W_fuse  = (const float*)d_in[19];
    const float* b_fuse  = (const float*)d_in[20];
    const float* ln_g    = (const float*)d_in[21];
    const float* ln_b    = (const float*)d_in[22];

    float* out    = (float*)d_out;
    float* fusion = out;
    float* o_tmu  = out + (size_t)SOUT;
    float* o_tsig = out + (size_t)2 * SOUT;
    float* o_imu  = out + (size_t)3 * SOUT;
    float* o_isig = out + (size_t)4 * SOUT;

    // workspace layout
    float* ws     = (float*)d_ws;
    float* fused  = ws;                            // SOUT fp32
    float* t_gate = ws + (size_t)SOUT;             // NTOK*8
    float* i_gate = t_gate + (size_t)NTOK * 8;
    unsigned short* tzb    = (unsigned short*)(i_gate + (size_t)NTOK * 8);  // SOUT bf16
    unsigned short* izb    = tzb + (size_t)SOUT;
    unsigned short* t_outb = izb + (size_t)SOUT;
    unsigned short* i_outb = t_outb + (size_t)SOUT;
    unsigned short* wt_t   = i_outb + (size_t)SOUT;     // 8*65536
    unsigned short* wt_i   = wt_t + (size_t)8 * 65536;
    unsigned short* wt_f   = wt_i + (size_t)8 * 65536;  // 512*256
    unsigned short* wt_muth = wt_f + (size_t)512 * 256; // 65536 each
    unsigned short* wt_mutl = wt_muth + 65536;
    unsigned short* wt_sgth = wt_mutl + 65536;
    unsigned short* wt_sgtl = wt_sgth + 65536;
    unsigned short* wt_muih = wt_sgtl + 65536;
    unsigned short* wt_muil = wt_muih + 65536;
    unsigned short* wt_sgih = wt_muil + 65536;
    unsigned short* wt_sgil = wt_sgih + 65536;

    prepW_kernel<<<dim3(16, 22), 256, 0, stream>>>(
        W_texp, W_iexp, W_mu_t, W_sg_t, W_mu_i, W_sg_i, W_fuse,
        wt_t, wt_i, wt_f,
        wt_muth, wt_mutl, wt_sgth, wt_sgtl,
        wt_muih, wt_muil, wt_sgih, wt_sgil);

    reparam_mfma_kernel<<<dim3(NTOK / 128, 2, 2), 256, 0, stream>>>(
        text, img,
        wt_muth, wt_mutl, wt_sgth, wt_sgtl,
        wt_muih, wt_muil, wt_sgih, wt_sgil,
        b_mu_t, b_sg_t, b_mu_i, b_sg_i, noise_t, noise_i,
        o_tmu, o_tsig, o_imu, o_isig, tzb, izb);

    gate_kernel<<<NTOK / 4, 256, 0, stream>>>(o_tmu, o_tsig, noise_t, W_gate, b_gate, t_gate);
    gate_kernel<<<NTOK / 4, 256, 0, stream>>>(o_imu, o_isig, noise_i, W_gate, b_gate, i_gate);

    expert_mfma_kernel<<<dim3(NTOK / 128, 2, 2), 256, 0, stream>>>(
        tzb, izb, wt_t, wt_i, b_texp, b_iexp, t_gate, i_gate, t_outb, i_outb);

    fusegemm_mfma_kernel<<<dim3(NTOK / 128, 2), 256, 0, stream>>>(
        t_outb, i_outb, wt_f, b_fuse, fused);

    ln_relu_res_kernel<<<NTOK / 4, 256, 0, stream>>>(fused, ln_g, ln_b, item, fusion);
}

// Round 5
// 161.195 us; speedup vs baseline: 4.1286x; 1.0276x over previous
//
#include <hip/hip_runtime.h>
#include <hip/hip_bf16.h>
#include <math.h>

#define NTOK 12800
#define HD 256
#define SOUT (NTOK * HD)

typedef __attribute__((ext_vector_type(8))) short short8_t;
typedef __attribute__((ext_vector_type(4))) float f32x4;

__device__ __forceinline__ unsigned short f2b(float f) {
    union { float f; unsigned u; } v; v.f = f;
    unsigned r = (v.u + 0x7FFFu + ((v.u >> 16) & 1u)) >> 16;
    return (unsigned short)r;
}
__device__ __forceinline__ float b2f(unsigned short s) {
    union { unsigned u; float f; } v; v.u = ((unsigned)s) << 16;
    return v.f;
}

// ---------------------------------------------------------------------------
// prepW: transpose+convert weights fp32 [k][d] -> bf16 [d][k].
// z 0..7 W_texp; 8..15 W_iexp; 16..19 packed reparam weights (hi+lo,
// rows 0-255 = mu, 256-511 = sg); 20..21 W_fuse halves ([256 d][512 k]).
// ---------------------------------------------------------------------------
__global__ __launch_bounds__(256) void prepW_kernel(
    const float* __restrict__ W_texp, const float* __restrict__ W_iexp,
    const float* __restrict__ W_mu_t, const float* __restrict__ W_sg_t,
    const float* __restrict__ W_mu_i, const float* __restrict__ W_sg_i,
    const float* __restrict__ W_fuse,
    unsigned short* __restrict__ wt_t, unsigned short* __restrict__ wt_i,
    unsigned short* __restrict__ wt_f,
    unsigned short* __restrict__ wpk_th, unsigned short* __restrict__ wpk_tl,
    unsigned short* __restrict__ wpk_ih, unsigned short* __restrict__ wpk_il)
{
    const int z = blockIdx.y;
    const float* src;
    unsigned short* dsth;
    unsigned short* dstl = nullptr;
    int dstride = 256, koff = 0, rowoff = 0;
    if (z < 8)       { src = W_texp + (size_t)z * 65536;       dsth = wt_t + (size_t)z * 65536; }
    else if (z < 16) { src = W_iexp + (size_t)(z - 8) * 65536; dsth = wt_i + (size_t)(z - 8) * 65536; }
    else if (z == 16){ src = W_mu_t; dsth = wpk_th; dstl = wpk_tl; }
    else if (z == 17){ src = W_sg_t; dsth = wpk_th; dstl = wpk_tl; rowoff = 256; }
    else if (z == 18){ src = W_mu_i; dsth = wpk_ih; dstl = wpk_il; }
    else if (z == 19){ src = W_sg_i; dsth = wpk_ih; dstl = wpk_il; rowoff = 256; }
    else if (z == 20){ src = W_fuse;         dsth = wt_f; dstride = 512; koff = 0;   }
    else             { src = W_fuse + 65536; dsth = wt_f; dstride = 512; koff = 256; }

    const int tk = (blockIdx.x >> 2) * 64;
    const int td = (blockIdx.x & 3) * 64;
    __shared__ float T[64][68];
    const int t = threadIdx.x;
    {
        const int r = t >> 2, c0 = (t & 3) * 16;
        const float* s = &src[(size_t)(tk + r) * 256 + td + c0];
#pragma unroll
        for (int j = 0; j < 4; ++j)
            *reinterpret_cast<float4*>(&T[r][c0 + j * 4]) =
                *reinterpret_cast<const float4*>(&s[j * 4]);
    }
    __syncthreads();
    {
        const int d = t & 63, kc = (t >> 6) * 16;
        union { unsigned short s[16]; short8_t v[2]; } uh, ul;
#pragma unroll
        for (int j = 0; j < 16; ++j) {
            const float x = T[kc + j][d];
            uh.s[j] = f2b(x);
            ul.s[j] = f2b(x - b2f(uh.s[j]));
        }
        unsigned short* p = &dsth[(size_t)(rowoff + td + d) * dstride + koff + tk + kc];
        *reinterpret_cast<short8_t*>(p) = uh.v[0];
        *reinterpret_cast<short8_t*>(p + 8) = uh.v[1];
        if (dstl) {
            unsigned short* q = &dstl[(size_t)(rowoff + td + d) * 256 + tk + kc];
            *reinterpret_cast<short8_t*>(q) = ul.v[0];
            *reinterpret_cast<short8_t*>(q + 8) = ul.v[1];
        }
    }
}

// ---------------------------------------------------------------------------
// cvt: A fp32 -> bf16 hi + residual lo (both modalities)
// ---------------------------------------------------------------------------
__global__ __launch_bounds__(256) void cvt_kernel(
    const float* __restrict__ text, const float* __restrict__ img,
    unsigned short* __restrict__ ah_t, unsigned short* __restrict__ al_t,
    unsigned short* __restrict__ ah_i, unsigned short* __restrict__ al_i)
{
    const int mod = blockIdx.y;
    const float* src = mod ? img : text;
    unsigned short* dh = mod ? ah_i : ah_t;
    unsigned short* dl = mod ? al_i : al_t;
    const size_t base = ((size_t)blockIdx.x * 256 + threadIdx.x) * 8;
    const float4 v0 = *reinterpret_cast<const float4*>(&src[base]);
    const float4 v1 = *reinterpret_cast<const float4*>(&src[base + 4]);
    const float x[8] = { v0.x, v0.y, v0.z, v0.w, v1.x, v1.y, v1.z, v1.w };
    union { unsigned short u[8]; short8_t v; } qh, ql;
#pragma unroll
    for (int c = 0; c < 8; ++c) {
        qh.u[c] = f2b(x[c]);
        ql.u[c] = f2b(x[c] - b2f(qh.u[c]));
    }
    *reinterpret_cast<short8_t*>(&dh[base]) = qh.v;
    *reinterpret_cast<short8_t*>(&dl[base]) = ql.v;
}

// ---------------------------------------------------------------------------
// reparam v2: split-precision MFMA (Ah*Wh + Ah*Wl + Al*Wh) on packed
// [Wmu|Wsg] (N=512). Tile 64(M) x 128(Npacked), grid 200x4x2 = 1600 blocks.
// Double-buffered LDS, 1 barrier per k-step.
// ---------------------------------------------------------------------------
__global__ __launch_bounds__(256) void reparam_mfma_kernel(
    const unsigned short* __restrict__ ah_t, const unsigned short* __restrict__ al_t,
    const unsigned short* __restrict__ ah_i, const unsigned short* __restrict__ al_i,
    const unsigned short* __restrict__ wpk_th, const unsigned short* __restrict__ wpk_tl,
    const unsigned short* __restrict__ wpk_ih, const unsigned short* __restrict__ wpk_il,
    const float* __restrict__ b_mu_t, const float* __restrict__ b_sg_t,
    const float* __restrict__ b_mu_i, const float* __restrict__ b_sg_i,
    float* __restrict__ o_tmu, float* __restrict__ o_tsig,
    float* __restrict__ o_imu, float* __restrict__ o_isig)
{
    const int mod = blockIdx.z;
    const unsigned short* Ah = mod ? ah_i : ah_t;
    const unsigned short* Al = mod ? al_i : al_t;
    const unsigned short* Wh = mod ? wpk_ih : wpk_th;
    const unsigned short* Wl = mod ? wpk_il : wpk_tl;
    const float* bmu = mod ? b_mu_i : b_mu_t;
    const float* bsg = mod ? b_sg_i : b_sg_t;
    float* omu = mod ? o_imu : o_tmu;
    float* osg = mod ? o_isig : o_tsig;

    __shared__ __align__(16) unsigned short AhS[2][4][64][8];   //  8 KB
    __shared__ __align__(16) unsigned short AlS[2][4][64][8];   //  8 KB
    __shared__ __align__(16) unsigned short BhS[2][4][128][8];  // 16 KB
    __shared__ __align__(16) unsigned short BlS[2][4][128][8];  // 16 KB

    const int tid = threadIdx.x;
    const int lane = tid & 63;
    const int w = tid >> 6;
    const int wr = w >> 1, wc = w & 1;
    const int lg = lane >> 4;
    const int lr = lane & 15;
    const int m0 = blockIdx.x * 64;
    const int n0 = blockIdx.y * 128;   // packed col space [0,512)

    const int ar = tid >> 2, akc = tid & 3;          // A staging map
    const int bn = tid >> 1, bk0 = (tid & 1) * 2;    // B staging map

    // prologue: stage ks=0 into buffer 0
    {
        *reinterpret_cast<short8_t*>(&AhS[0][akc][ar][0]) =
            *reinterpret_cast<const short8_t*>(&Ah[(size_t)(m0 + ar) * HD + akc * 8]);
        *reinterpret_cast<short8_t*>(&AlS[0][akc][ar][0]) =
            *reinterpret_cast<const short8_t*>(&Al[(size_t)(m0 + ar) * HD + akc * 8]);
#pragma unroll
        for (int j = 0; j < 2; ++j) {
            const int kc = bk0 + j;
            *reinterpret_cast<short8_t*>(&BhS[0][kc][bn][0]) =
                *reinterpret_cast<const short8_t*>(&Wh[(size_t)(n0 + bn) * HD + kc * 8]);
            *reinterpret_cast<short8_t*>(&BlS[0][kc][bn][0]) =
                *reinterpret_cast<const short8_t*>(&Wl[(size_t)(n0 + bn) * HD + kc * 8]);
        }
    }
    __syncthreads();

    f32x4 acc[2][4];
#pragma unroll
    for (int mi = 0; mi < 2; ++mi)
#pragma unroll
        for (int ni = 0; ni < 4; ++ni)
            acc[mi][ni] = (f32x4){0.f, 0.f, 0.f, 0.f};

    for (int ks = 0; ks < 8; ++ks) {
        const int cur = ks & 1;
        // issue next-step global loads early
        short8_t rah, ral, rbh[2], rbl[2];
        if (ks < 7) {
            const int k1 = (ks + 1) * 32;
            rah = *reinterpret_cast<const short8_t*>(&Ah[(size_t)(m0 + ar) * HD + k1 + akc * 8]);
            ral = *reinterpret_cast<const short8_t*>(&Al[(size_t)(m0 + ar) * HD + k1 + akc * 8]);
#pragma unroll
            for (int j = 0; j < 2; ++j) {
                const int kc = bk0 + j;
                rbh[j] = *reinterpret_cast<const short8_t*>(&Wh[(size_t)(n0 + bn) * HD + k1 + kc * 8]);
                rbl[j] = *reinterpret_cast<const short8_t*>(&Wl[(size_t)(n0 + bn) * HD + k1 + kc * 8]);
            }
        }
        // fragment reads + MFMA on current buffer
        short8_t ahf[2], alf[2], bhf[4], blf[4];
#pragma unroll
        for (int mi = 0; mi < 2; ++mi) {
            ahf[mi] = *reinterpret_cast<const short8_t*>(&AhS[cur][lg][wr * 32 + mi * 16 + lr][0]);
            alf[mi] = *reinterpret_cast<const short8_t*>(&AlS[cur][lg][wr * 32 + mi * 16 + lr][0]);
        }
#pragma unroll
        for (int ni = 0; ni < 4; ++ni) {
            bhf[ni] = *reinterpret_cast<const short8_t*>(&BhS[cur][lg][wc * 64 + ni * 16 + lr][0]);
            blf[ni] = *reinterpret_cast<const short8_t*>(&BlS[cur][lg][wc * 64 + ni * 16 + lr][0]);
        }
#pragma unroll
        for (int mi = 0; mi < 2; ++mi)
#pragma unroll
            for (int ni = 0; ni < 4; ++ni) {
                acc[mi][ni] = __builtin_amdgcn_mfma_f32_16x16x32_bf16(ahf[mi], bhf[ni], acc[mi][ni], 0, 0, 0);
                acc[mi][ni] = __builtin_amdgcn_mfma_f32_16x16x32_bf16(ahf[mi], blf[ni], acc[mi][ni], 0, 0, 0);
                acc[mi][ni] = __builtin_amdgcn_mfma_f32_16x16x32_bf16(alf[mi], bhf[ni], acc[mi][ni], 0, 0, 0);
            }
        // write next buffer (no conflict with current readers)
        if (ks < 7) {
            const int nxt = cur ^ 1;
            *reinterpret_cast<short8_t*>(&AhS[nxt][akc][ar][0]) = rah;
            *reinterpret_cast<short8_t*>(&AlS[nxt][akc][ar][0]) = ral;
#pragma unroll
            for (int j = 0; j < 2; ++j) {
                const int kc = bk0 + j;
                *reinterpret_cast<short8_t*>(&BhS[nxt][kc][bn][0]) = rbh[j];
                *reinterpret_cast<short8_t*>(&BlS[nxt][kc][bn][0]) = rbl[j];
            }
        }
        __syncthreads();
    }

    // epilogue: bias (+ exp for sg half). Branch is block-uniform (n0 window).
    const bool is_sg = (n0 >= 256);
    float bv[4];
    int cc[4];
#pragma unroll
    for (int ni = 0; ni < 4; ++ni) {
        const int dpk = n0 + wc * 64 + ni * 16 + lr;
        cc[ni] = is_sg ? dpk - 256 : dpk;
        bv[ni] = is_sg ? bsg[cc[ni]] : bmu[cc[ni]];
    }
    float* outp = is_sg ? osg : omu;
#pragma unroll
    for (int mi = 0; mi < 2; ++mi)
#pragma unroll
        for (int r = 0; r < 4; ++r) {
            const int row = m0 + wr * 32 + mi * 16 + lg * 4 + r;
#pragma unroll
            for (int ni = 0; ni < 4; ++ni) {
                const float v = acc[mi][ni][r] + bv[ni];
                outp[(size_t)row * HD + cc[ni]] = is_sg ? expf(v) : v;
            }
        }
}

// ---------------------------------------------------------------------------
// gating: z = mu + sig*noise (fp32) -> logits -> softmax -> top2 -> renorm.
// Also emits zb (bf16 z) for the expert kernel. Both modalities (blockIdx.y).
// ---------------------------------------------------------------------------
__global__ __launch_bounds__(256) void gate_kernel(
    const float* __restrict__ o_tmu, const float* __restrict__ o_tsig,
    const float* __restrict__ o_imu, const float* __restrict__ o_isig,
    const float* __restrict__ noise_t, const float* __restrict__ noise_i,
    const float* __restrict__ Wg, const float* __restrict__ bg,
    float* __restrict__ t_gate, float* __restrict__ i_gate,
    unsigned short* __restrict__ tzb, unsigned short* __restrict__ izb)
{
    const int mod = blockIdx.y;
    const float* mu    = mod ? o_imu  : o_tmu;
    const float* sig   = mod ? o_isig : o_tsig;
    const float* noise = mod ? noise_i : noise_t;
    float* gate        = mod ? i_gate : t_gate;
    unsigned short* zb = mod ? izb : tzb;

    const int lane = threadIdx.x & 63;
    const int n = blockIdx.x * 4 + (threadIdx.x >> 6);
    const size_t off = (size_t)n * HD + lane * 4;
    const float4 m4 = *reinterpret_cast<const float4*>(&mu[off]);
    const float4 s4 = *reinterpret_cast<const float4*>(&sig[off]);
    const float4 n4 = *reinterpret_cast<const float4*>(&noise[off]);
    const float zz[4] = { fmaf(s4.x, n4.x, m4.x), fmaf(s4.y, n4.y, m4.y),
                          fmaf(s4.z, n4.z, m4.z), fmaf(s4.w, n4.w, m4.w) };
    ushort4 zb4;
    zb4.x = f2b(zz[0]); zb4.y = f2b(zz[1]); zb4.z = f2b(zz[2]); zb4.w = f2b(zz[3]);
    *reinterpret_cast<ushort4*>(&zb[off]) = zb4;

    float lg[8];
#pragma unroll
    for (int e = 0; e < 8; ++e) lg[e] = 0.f;
#pragma unroll
    for (int i = 0; i < 4; ++i) {
        const float* wr = &Wg[(size_t)(lane * 4 + i) * 8];
        const float4 w0 = *reinterpret_cast<const float4*>(wr);
        const float4 w1 = *reinterpret_cast<const float4*>(wr + 4);
        lg[0] = fmaf(zz[i], w0.x, lg[0]); lg[1] = fmaf(zz[i], w0.y, lg[1]);
        lg[2] = fmaf(zz[i], w0.z, lg[2]); lg[3] = fmaf(zz[i], w0.w, lg[3]);
        lg[4] = fmaf(zz[i], w1.x, lg[4]); lg[5] = fmaf(zz[i], w1.y, lg[5]);
        lg[6] = fmaf(zz[i], w1.z, lg[6]); lg[7] = fmaf(zz[i], w1.w, lg[7]);
    }
#pragma unroll
    for (int off2 = 32; off2; off2 >>= 1)
#pragma unroll
        for (int e = 0; e < 8; ++e) lg[e] += __shfl_down(lg[e], off2);

    if (lane == 0) {
        float m = -1e30f;
#pragma unroll
        for (int e = 0; e < 8; ++e) { lg[e] += bg[e]; m = fmaxf(m, lg[e]); }
        float p[8], s = 0.f;
#pragma unroll
        for (int e = 0; e < 8; ++e) { p[e] = expf(lg[e] - m); s += p[e]; }
        const float inv_s = 1.f / s;
#pragma unroll
        for (int e = 0; e < 8; ++e) p[e] *= inv_s;
        int e1 = 0;
#pragma unroll
        for (int e = 1; e < 8; ++e) if (p[e] > p[e1]) e1 = e;
        int e2 = (e1 == 0) ? 1 : 0;
#pragma unroll
        for (int e = 0; e < 8; ++e) if (e != e1 && p[e] > p[e2]) e2 = e;
        const float denom = 1.f / (p[e1] + p[e2] + 1e-8f);
        float g[8];
#pragma unroll
        for (int e = 0; e < 8; ++e) g[e] = 0.f;
        g[e1] = p[e1] * denom; g[e2] = p[e2] * denom;
        float* gr = &gate[(size_t)n * 8];
        *reinterpret_cast<float4*>(gr)     = make_float4(g[0], g[1], g[2], g[3]);
        *reinterpret_cast<float4*>(gr + 4) = make_float4(g[4], g[5], g[6], g[7]);
    }
}

// ---------------------------------------------------------------------------
// experts v2: tile 64(M) x 128(N), grid 200x2x2 = 800 blocks. A full-K
// resident; B double-buffered, 1 barrier per k-step, flattened (e,ks) loop.
// ---------------------------------------------------------------------------
__global__ __launch_bounds__(256) void expert_mfma_kernel(
    const unsigned short* __restrict__ tzb, const unsigned short* __restrict__ izb,
    const unsigned short* __restrict__ wt_t, const unsigned short* __restrict__ wt_i,
    const float* __restrict__ bx_t, const float* __restrict__ bx_i,
    const float* __restrict__ g_t, const float* __restrict__ g_i,
    unsigned short* __restrict__ out_t, unsigned short* __restrict__ out_i)
{
    const int mod = blockIdx.z;
    const unsigned short* Zb = mod ? izb : tzb;
    const unsigned short* Wt = mod ? wt_i : wt_t;
    const float* bx   = mod ? bx_i : bx_t;
    const float* gate = mod ? g_i  : g_t;
    unsigned short* outp = mod ? out_i : out_t;

    __shared__ __align__(16) unsigned short AlS[32][64][8];     // 32 KB
    __shared__ __align__(16) unsigned short BlS[2][4][128][8];  // 16 KB
    __shared__ float gld[64][8];                                //  2 KB

    const int tid = threadIdx.x;
    const int lane = tid & 63;
    const int w = tid >> 6;
    const int wr = w >> 1, wc = w & 1;
    const int lg = lane >> 4;
    const int lr = lane & 15;
    const int m0 = blockIdx.x * 64;
    const int n0 = blockIdx.y * 128;

    const int bn = tid >> 1, bk0 = (tid & 1) * 2;

    // stage A (full K) + gate tile + B(kk=0)
    {
        const int r = tid >> 2, kcg = tid & 3;
        const unsigned short* src = &Zb[(size_t)(m0 + r) * HD + kcg * 64];
#pragma unroll
        for (int j = 0; j < 8; ++j)
            *reinterpret_cast<short8_t*>(&AlS[kcg * 8 + j][r][0]) =
                *reinterpret_cast<const short8_t*>(&src[j * 8]);
    }
    if (tid < 128)
        reinterpret_cast<float4*>(&gld[0][0])[tid] =
            reinterpret_cast<const float4*>(&gate[(size_t)m0 * 8])[tid];
    {
        const unsigned short* We = Wt + (size_t)n0 * HD;  // e=0, ks=0
#pragma unroll
        for (int j = 0; j < 2; ++j) {
            const int kc = bk0 + j;
            *reinterpret_cast<short8_t*>(&BlS[0][kc][bn][0]) =
                *reinterpret_cast<const short8_t*>(&We[(size_t)bn * HD + kc * 8]);
        }
    }
    __syncthreads();

    f32x4 acc[2][4], accT[2][4];
#pragma unroll
    for (int mi = 0; mi < 2; ++mi)
#pragma unroll
        for (int ni = 0; ni < 4; ++ni) {
            acc[mi][ni]  = (f32x4){0.f, 0.f, 0.f, 0.f};
            accT[mi][ni] = (f32x4){0.f, 0.f, 0.f, 0.f};
        }

    for (int kk = 0; kk < 64; ++kk) {
        const int cur = kk & 1;
        const int e = kk >> 3, ks = kk & 7;
        // prefetch kk+1
        short8_t rb[2];
        if (kk < 63) {
            const int e2 = (kk + 1) >> 3, ks2 = (kk + 1) & 7;
            const unsigned short* We2 = Wt + (size_t)e2 * HD * HD + (size_t)n0 * HD;
#pragma unroll
            for (int j = 0; j < 2; ++j) {
                const int kc = bk0 + j;
                rb[j] = *reinterpret_cast<const short8_t*>(
                    &We2[(size_t)bn * HD + ks2 * 32 + kc * 8]);
            }
        }
        // fragments + MFMA
        short8_t af[2], bf[4];
#pragma unroll
        for (int mi = 0; mi < 2; ++mi)
            af[mi] = *reinterpret_cast<const short8_t*>(
                &AlS[ks * 4 + lg][wr * 32 + mi * 16 + lr][0]);
#pragma unroll
        for (int ni = 0; ni < 4; ++ni)
            bf[ni] = *reinterpret_cast<const short8_t*>(
                &BlS[cur][lg][wc * 64 + ni * 16 + lr][0]);
#pragma unroll
        for (int mi = 0; mi < 2; ++mi)
#pragma unroll
            for (int ni = 0; ni < 4; ++ni)
                acc[mi][ni] = __builtin_amdgcn_mfma_f32_16x16x32_bf16(
                    af[mi], bf[ni], acc[mi][ni], 0, 0, 0);
        // stage next buffer
        if (kk < 63) {
            const int nxt = cur ^ 1;
#pragma unroll
            for (int j = 0; j < 2; ++j)
                *reinterpret_cast<short8_t*>(&BlS[nxt][bk0 + j][bn][0]) = rb[j];
        }
        // expert boundary: gate-weight + bias combine
        if (ks == 7) {
#pragma unroll
            for (int mi = 0; mi < 2; ++mi) {
                const int rb2 = wr * 32 + mi * 16 + lg * 4;
                const float gv0 = gld[rb2 + 0][e];
                const float gv1 = gld[rb2 + 1][e];
                const float gv2 = gld[rb2 + 2][e];
                const float gv3 = gld[rb2 + 3][e];
#pragma unroll
                for (int ni = 0; ni < 4; ++ni) {
                    const float bv = bx[(size_t)e * HD + n0 + wc * 64 + ni * 16 + lr];
                    accT[mi][ni][0] += gv0 * (acc[mi][ni][0] + bv);
                    accT[mi][ni][1] += gv1 * (acc[mi][ni][1] + bv);
                    accT[mi][ni][2] += gv2 * (acc[mi][ni][2] + bv);
                    accT[mi][ni][3] += gv3 * (acc[mi][ni][3] + bv);
                    acc[mi][ni] = (f32x4){0.f, 0.f, 0.f, 0.f};
                }
            }
        }
        __syncthreads();
    }

#pragma unroll
    for (int mi = 0; mi < 2; ++mi)
#pragma unroll
        for (int ni = 0; ni < 4; ++ni)
#pragma unroll
            for (int r = 0; r < 4; ++r)
                outp[(size_t)(m0 + wr * 32 + mi * 16 + lg * 4 + r) * HD
                     + n0 + wc * 64 + ni * 16 + lr] = f2b(accT[mi][ni][r]);
}

// ---------------------------------------------------------------------------
// fuse GEMM v2: fused = [t_out|i_out](bf16) @ WfT + bf  (K=512), tile 64x128,
// double-buffered, 1 barrier per k-step. grid 200x2.
// ---------------------------------------------------------------------------
__global__ __launch_bounds__(256) void fusegemm_mfma_kernel(
    const unsigned short* __restrict__ t_outb, const unsigned short* __restrict__ i_outb,
    const unsigned short* __restrict__ wtf, const float* __restrict__ bfuse,
    float* __restrict__ fused)
{
    __shared__ __align__(16) unsigned short AS[2][8][64][8];   // 16 KB
    __shared__ __align__(16) unsigned short BS[2][8][128][8];  // 32 KB

    const int tid = threadIdx.x;
    const int lane = tid & 63;
    const int w = tid >> 6;
    const int wr = w >> 1, wc = w & 1;
    const int lg = lane >> 4;
    const int lr = lane & 15;
    const int m0 = blockIdx.x * 64;
    const int n0 = blockIdx.y * 128;

    const int ar = tid >> 2, akc0 = (tid & 3) * 2;   // A: 2 chunks/thread
    const int bn = tid >> 1, bkc0 = (tid & 1) * 4;   // B: 4 chunks/thread

    // prologue: stage ks=0
    {
        const unsigned short* base = t_outb;
#pragma unroll
        for (int j = 0; j < 2; ++j) {
            const int kc = akc0 + j;
            *reinterpret_cast<short8_t*>(&AS[0][kc][ar][0]) =
                *reinterpret_cast<const short8_t*>(&base[(size_t)(m0 + ar) * HD + kc * 8]);
        }
#pragma unroll
        for (int j = 0; j < 4; ++j) {
            const int kc = bkc0 + j;
            *reinterpret_cast<short8_t*>(&BS[0][kc][bn][0]) =
                *reinterpret_cast<const short8_t*>(&wtf[(size_t)(n0 + bn) * 512 + kc * 8]);
        }
    }
    __syncthreads();

    f32x4 acc[2][4];
#pragma unroll
    for (int mi = 0; mi < 2; ++mi)
#pragma unroll
        for (int ni = 0; ni < 4; ++ni)
            acc[mi][ni] = (f32x4){0.f, 0.f, 0.f, 0.f};

    for (int ks = 0; ks < 8; ++ks) {
        const int cur = ks & 1;
        short8_t ra[2], rbv[4];
        if (ks < 7) {
            const int ks2 = ks + 1;
            const unsigned short* base = (ks2 < 4) ? t_outb : i_outb;
            const int kloc = (ks2 & 3) * 64;
#pragma unroll
            for (int j = 0; j < 2; ++j) {
                const int kc = akc0 + j;
                ra[j] = *reinterpret_cast<const short8_t*>(
                    &base[(size_t)(m0 + ar) * HD + kloc + kc * 8]);
            }
#pragma unroll
            for (int j = 0; j < 4; ++j) {
                const int kc = bkc0 + j;
                rbv[j] = *reinterpret_cast<const short8_t*>(
                    &wtf[(size_t)(n0 + bn) * 512 + ks2 * 64 + kc * 8]);
            }
        }
#pragma unroll
        for (int s = 0; s < 2; ++s) {
            short8_t af[2], bf[4];
#pragma unroll
            for (int mi = 0; mi < 2; ++mi)
                af[mi] = *reinterpret_cast<const short8_t*>(
                    &AS[cur][s * 4 + lg][wr * 32 + mi * 16 + lr][0]);
#pragma unroll
            for (int ni = 0; ni < 4; ++ni)
                bf[ni] = *reinterpret_cast<const short8_t*>(
                    &BS[cur][s * 4 + lg][wc * 64 + ni * 16 + lr][0]);
#pragma unroll
            for (int mi = 0; mi < 2; ++mi)
#pragma unroll
                for (int ni = 0; ni < 4; ++ni)
                    acc[mi][ni] = __builtin_amdgcn_mfma_f32_16x16x32_bf16(
                        af[mi], bf[ni], acc[mi][ni], 0, 0, 0);
        }
        if (ks < 7) {
            const int nxt = cur ^ 1;
#pragma unroll
            for (int j = 0; j < 2; ++j)
                *reinterpret_cast<short8_t*>(&AS[nxt][akc0 + j][ar][0]) = ra[j];
#pragma unroll
            for (int j = 0; j < 4; ++j)
                *reinterpret_cast<short8_t*>(&BS[nxt][bkc0 + j][bn][0]) = rbv[j];
        }
        __syncthreads();
    }

    float bv[4];
    int cc[4];
#pragma unroll
    for (int ni = 0; ni < 4; ++ni) {
        cc[ni] = n0 + wc * 64 + ni * 16 + lr;
        bv[ni] = bfuse[cc[ni]];
    }
#pragma unroll
    for (int mi = 0; mi < 2; ++mi)
#pragma unroll
        for (int r = 0; r < 4; ++r) {
            const int row = m0 + wr * 32 + mi * 16 + lg * 4 + r;
#pragma unroll
            for (int ni = 0; ni < 4; ++ni)
                fused[(size_t)row * HD + cc[ni]] = acc[mi][ni][r] + bv[ni];
        }
}

// ---------------------------------------------------------------------------
// LN -> ReLU -> +item
// ---------------------------------------------------------------------------
__global__ __launch_bounds__(256) void ln_relu_res_kernel(
    const float* __restrict__ fused, const float* __restrict__ g,
    const float* __restrict__ b, const float* __restrict__ item,
    float* __restrict__ fusion)
{
    const int lane = threadIdx.x & 63;
    const int n = blockIdx.x * 4 + (threadIdx.x >> 6);
    const size_t off = (size_t)n * HD + lane * 4;
    const float4 x = *reinterpret_cast<const float4*>(&fused[off]);
    float s = x.x + x.y + x.z + x.w;
    float ss = x.x * x.x + x.y * x.y + x.z * x.z + x.w * x.w;
#pragma unroll
    for (int o = 32; o; o >>= 1) { s += __shfl_xor(s, o); ss += __shfl_xor(ss, o); }
    const float mean = s * (1.f / 256.f);
    const float var = ss * (1.f / 256.f) - mean * mean;
    const float rstd = rsqrtf(var + 1e-5f);
    const float4 gg = *reinterpret_cast<const float4*>(&g[lane * 4]);
    const float4 bb = *reinterpret_cast<const float4*>(&b[lane * 4]);
    const float4 it = *reinterpret_cast<const float4*>(&item[off]);
    float4 o4;
    o4.x = fmaxf((x.x - mean) * rstd * gg.x + bb.x, 0.f) + it.x;
    o4.y = fmaxf((x.y - mean) * rstd * gg.y + bb.y, 0.f) + it.y;
    o4.z = fmaxf((x.z - mean) * rstd * gg.z + bb.z, 0.f) + it.z;
    o4.w = fmaxf((x.w - mean) * rstd * gg.w + bb.w, 0.f) + it.w;
    *reinterpret_cast<float4*>(&fusion[off]) = o4;
}

// ---------------------------------------------------------------------------
extern "C" void kernel_launch(void* const* d_in, const int* in_sizes, int n_in,
                              void* d_out, int out_size, void* d_ws, size_t ws_size,
                              hipStream_t stream)
{
    const float* text    = (const float*)d_in[0];
    const float* img     = (const float*)d_in[1];
    const float* item    = (const float*)d_in[2];
    const float* noise_t = (const float*)d_in[3];
    const float* noise_i = (const float*)d_in[4];
    const float* W_mu_t  = (const float*)d_in[5];
    const float* b_mu_t  = (const float*)d_in[6];
    const float* W_sg_t  = (const float*)d_in[7];
    const float* b_sg_t  = (const float*)d_in[8];
    const float* W_mu_i  = (const float*)d_in[9];
    const float* b_mu_i  = (const float*)d_in[10];
    const float* W_sg_i  = (const float*)d_in[11];
    const float* b_sg_i  = (const float*)d_in[12];
    const float* W_gate  = (const float*)d_in[13];
    const float* b_gate  = (const float*)d_in[14];
    const float* W_texp  = (const float*)d_in[15];
    const float* b_texp  = (const float*)d_in[16];
    const float* W_iexp  = (const float*)d_in[17];
    const float* b_iexp  = (const float*)d_in[18];
    const float* W_fuse  = (const float*)d_in[19];
    const float* b_fuse  = (const float*)d_in[20];
    const float* ln_g    = (const float*)d_in[21];
    const float* ln_b    = (const float*)d_in[22];

    float* out    = (float*)d_out;
    float* fusion = out;
    float* o_tmu  = out + (size_t)SOUT;
    float* o_tsig = out + (size_t)2 * SOUT;
    float* o_imu  = out + (size_t)3 * SOUT;
    float* o_isig = out + (size_t)4 * SOUT;

    // workspace layout (with phase-based aliasing):
    // bufA: Ah_t (cvt/reparam) -> t_outb (expert/fuse)
    // bufB: Al_t               -> i_outb
    // bufC: Ah_i + Al_i        -> fused (fp32)
    unsigned short* bufA = (unsigned short*)d_ws;
    unsigned short* bufB = bufA + (size_t)SOUT;
    unsigned short* bufC = bufB + (size_t)SOUT;
    unsigned short* tzb  = bufC + (size_t)2 * SOUT;
    unsigned short* izb  = tzb + (size_t)SOUT;
    float* t_gate = (float*)(izb + (size_t)SOUT);
    float* i_gate = t_gate + (size_t)NTOK * 8;
    unsigned short* wt_t   = (unsigned short*)(i_gate + (size_t)NTOK * 8);
    unsigned short* wt_i   = wt_t + (size_t)8 * 65536;
    unsigned short* wt_f   = wt_i + (size_t)8 * 65536;   // 256 x 512
    unsigned short* wpk_th = wt_f + (size_t)131072;      // 512 x 256 each
    unsigned short* wpk_tl = wpk_th + (size_t)131072;
    unsigned short* wpk_ih = wpk_tl + (size_t)131072;
    unsigned short* wpk_il = wpk_ih + (size_t)131072;

    unsigned short* ah_t = bufA;
    unsigned short* al_t = bufB;
    unsigned short* ah_i = bufC;
    unsigned short* al_i = bufC + (size_t)SOUT;
    unsigned short* t_outb = bufA;
    unsigned short* i_outb = bufB;
    float* fused = (float*)bufC;

    prepW_kernel<<<dim3(16, 22), 256, 0, stream>>>(
        W_texp, W_iexp, W_mu_t, W_sg_t, W_mu_i, W_sg_i, W_fuse,
        wt_t, wt_i, wt_f, wpk_th, wpk_tl, wpk_ih, wpk_il);

    cvt_kernel<<<dim3(SOUT / 2048, 2), 256, 0, stream>>>(
        text, img, ah_t, al_t, ah_i, al_i);

    reparam_mfma_kernel<<<dim3(NTOK / 64, 4, 2), 256, 0, stream>>>(
        ah_t, al_t, ah_i, al_i, wpk_th, wpk_tl, wpk_ih, wpk_il,
        b_mu_t, b_sg_t, b_mu_i, b_sg_i,
        o_tmu, o_tsig, o_imu, o_isig);

    gate_kernel<<<dim3(NTOK / 4, 2), 256, 0, stream>>>(
        o_tmu, o_tsig, o_imu, o_isig, noise_t, noise_i,
        W_gate, b_gate, t_gate, i_gate, tzb, izb);

    expert_mfma_kernel<<<dim3(NTOK / 64, 2, 2), 256, 0, stream>>>(
        tzb, izb, wt_t, wt_i, b_texp, b_iexp, t_gate, i_gate, t_outb, i_outb);

    fusegemm_mfma_kernel<<<dim3(NTOK / 64, 2), 256, 0, stream>>>(
        t_outb, i_outb, wt_f, b_fuse, fused);

    ln_relu_res_kernel<<<NTOK / 4, 256, 0, stream>>>(fused, ln_g, ln_b, item, fusion);
}

// Round 6
// 152.700 us; speedup vs baseline: 4.3583x; 1.0556x over previous
//
#include <hip/hip_runtime.h>
#include <hip/hip_bf16.h>
#include <math.h>

#define NTOK 12800
#define HD 256
#define SOUT (NTOK * HD)

typedef __attribute__((ext_vector_type(8))) short short8_t;
typedef __attribute__((ext_vector_type(4))) float f32x4;

__device__ __forceinline__ unsigned short f2b(float f) {
    union { float f; unsigned u; } v; v.f = f;
    unsigned r = (v.u + 0x7FFFu + ((v.u >> 16) & 1u)) >> 16;
    return (unsigned short)r;
}
__device__ __forceinline__ float b2f(unsigned short s) {
    union { unsigned u; float f; } v; v.u = ((unsigned)s) << 16;
    return v.f;
}
__device__ __forceinline__ void glds16(const void* g, void* l) {
    __builtin_amdgcn_global_load_lds(
        (const __attribute__((address_space(1))) void*)g,
        (__attribute__((address_space(3))) void*)l, 16, 0, 0);
}

// ---------------------------------------------------------------------------
// prepW: transpose+convert weights fp32 [k][d] -> bf16 [d][k].
// z 0..7 W_texp; 8..15 W_iexp; 16..19 packed reparam weights (hi+lo,
// rows 0-255 = mu, 256-511 = sg); 20..21 W_fuse halves ([256 d][512 k]).
// ---------------------------------------------------------------------------
__global__ __launch_bounds__(256) void prepW_kernel(
    const float* __restrict__ W_texp, const float* __restrict__ W_iexp,
    const float* __restrict__ W_mu_t, const float* __restrict__ W_sg_t,
    const float* __restrict__ W_mu_i, const float* __restrict__ W_sg_i,
    const float* __restrict__ W_fuse,
    unsigned short* __restrict__ wt_t, unsigned short* __restrict__ wt_i,
    unsigned short* __restrict__ wt_f,
    unsigned short* __restrict__ wpk_th, unsigned short* __restrict__ wpk_tl,
    unsigned short* __restrict__ wpk_ih, unsigned short* __restrict__ wpk_il)
{
    const int z = blockIdx.y;
    const float* src;
    unsigned short* dsth;
    unsigned short* dstl = nullptr;
    int dstride = 256, koff = 0, rowoff = 0;
    if (z < 8)       { src = W_texp + (size_t)z * 65536;       dsth = wt_t + (size_t)z * 65536; }
    else if (z < 16) { src = W_iexp + (size_t)(z - 8) * 65536; dsth = wt_i + (size_t)(z - 8) * 65536; }
    else if (z == 16){ src = W_mu_t; dsth = wpk_th; dstl = wpk_tl; }
    else if (z == 17){ src = W_sg_t; dsth = wpk_th; dstl = wpk_tl; rowoff = 256; }
    else if (z == 18){ src = W_mu_i; dsth = wpk_ih; dstl = wpk_il; }
    else if (z == 19){ src = W_sg_i; dsth = wpk_ih; dstl = wpk_il; rowoff = 256; }
    else if (z == 20){ src = W_fuse;         dsth = wt_f; dstride = 512; koff = 0;   }
    else             { src = W_fuse + 65536; dsth = wt_f; dstride = 512; koff = 256; }

    const int tk = (blockIdx.x >> 2) * 64;
    const int td = (blockIdx.x & 3) * 64;
    __shared__ float T[64][68];
    const int t = threadIdx.x;
    {
        const int r = t >> 2, c0 = (t & 3) * 16;
        const float* s = &src[(size_t)(tk + r) * 256 + td + c0];
#pragma unroll
        for (int j = 0; j < 4; ++j)
            *reinterpret_cast<float4*>(&T[r][c0 + j * 4]) =
                *reinterpret_cast<const float4*>(&s[j * 4]);
    }
    __syncthreads();
    {
        const int d = t & 63, kc = (t >> 6) * 16;
        union { unsigned short s[16]; short8_t v[2]; } uh, ul;
#pragma unroll
        for (int j = 0; j < 16; ++j) {
            const float x = T[kc + j][d];
            uh.s[j] = f2b(x);
            ul.s[j] = f2b(x - b2f(uh.s[j]));
        }
        unsigned short* p = &dsth[(size_t)(rowoff + td + d) * dstride + koff + tk + kc];
        *reinterpret_cast<short8_t*>(p) = uh.v[0];
        *reinterpret_cast<short8_t*>(p + 8) = uh.v[1];
        if (dstl) {
            unsigned short* q = &dstl[(size_t)(rowoff + td + d) * 256 + tk + kc];
            *reinterpret_cast<short8_t*>(q) = ul.v[0];
            *reinterpret_cast<short8_t*>(q + 8) = ul.v[1];
        }
    }
}

// ---------------------------------------------------------------------------
// cvt: A fp32 -> bf16 hi + residual lo (both modalities)
// ---------------------------------------------------------------------------
__global__ __launch_bounds__(256) void cvt_kernel(
    const float* __restrict__ text, const float* __restrict__ img,
    unsigned short* __restrict__ ah_t, unsigned short* __restrict__ al_t,
    unsigned short* __restrict__ ah_i, unsigned short* __restrict__ al_i)
{
    const int mod = blockIdx.y;
    const float* src = mod ? img : text;
    unsigned short* dh = mod ? ah_i : ah_t;
    unsigned short* dl = mod ? al_i : al_t;
    const size_t base = ((size_t)blockIdx.x * 256 + threadIdx.x) * 8;
    const float4 v0 = *reinterpret_cast<const float4*>(&src[base]);
    const float4 v1 = *reinterpret_cast<const float4*>(&src[base + 4]);
    const float x[8] = { v0.x, v0.y, v0.z, v0.w, v1.x, v1.y, v1.z, v1.w };
    union { unsigned short u[8]; short8_t v; } qh, ql;
#pragma unroll
    for (int c = 0; c < 8; ++c) {
        qh.u[c] = f2b(x[c]);
        ql.u[c] = f2b(x[c] - b2f(qh.u[c]));
    }
    *reinterpret_cast<short8_t*>(&dh[base]) = qh.v;
    *reinterpret_cast<short8_t*>(&dl[base]) = ql.v;
}

// ---------------------------------------------------------------------------
// reparam v2 (unchanged from R5): split-precision MFMA on packed [Wmu|Wsg]
// ---------------------------------------------------------------------------
__global__ __launch_bounds__(256) void reparam_mfma_kernel(
    const unsigned short* __restrict__ ah_t, const unsigned short* __restrict__ al_t,
    const unsigned short* __restrict__ ah_i, const unsigned short* __restrict__ al_i,
    const unsigned short* __restrict__ wpk_th, const unsigned short* __restrict__ wpk_tl,
    const unsigned short* __restrict__ wpk_ih, const unsigned short* __restrict__ wpk_il,
    const float* __restrict__ b_mu_t, const float* __restrict__ b_sg_t,
    const float* __restrict__ b_mu_i, const float* __restrict__ b_sg_i,
    float* __restrict__ o_tmu, float* __restrict__ o_tsig,
    float* __restrict__ o_imu, float* __restrict__ o_isig)
{
    const int mod = blockIdx.z;
    const unsigned short* Ah = mod ? ah_i : ah_t;
    const unsigned short* Al = mod ? al_i : al_t;
    const unsigned short* Wh = mod ? wpk_ih : wpk_th;
    const unsigned short* Wl = mod ? wpk_il : wpk_tl;
    const float* bmu = mod ? b_mu_i : b_mu_t;
    const float* bsg = mod ? b_sg_i : b_sg_t;
    float* omu = mod ? o_imu : o_tmu;
    float* osg = mod ? o_isig : o_tsig;

    __shared__ __align__(16) unsigned short AhS[2][4][64][8];
    __shared__ __align__(16) unsigned short AlS[2][4][64][8];
    __shared__ __align__(16) unsigned short BhS[2][4][128][8];
    __shared__ __align__(16) unsigned short BlS[2][4][128][8];

    const int tid = threadIdx.x;
    const int lane = tid & 63;
    const int w = tid >> 6;
    const int wr = w >> 1, wc = w & 1;
    const int lg = lane >> 4;
    const int lr = lane & 15;
    const int m0 = blockIdx.x * 64;
    const int n0 = blockIdx.y * 128;

    const int ar = tid >> 2, akc = tid & 3;
    const int bn = tid >> 1, bk0 = (tid & 1) * 2;

    {
        *reinterpret_cast<short8_t*>(&AhS[0][akc][ar][0]) =
            *reinterpret_cast<const short8_t*>(&Ah[(size_t)(m0 + ar) * HD + akc * 8]);
        *reinterpret_cast<short8_t*>(&AlS[0][akc][ar][0]) =
            *reinterpret_cast<const short8_t*>(&Al[(size_t)(m0 + ar) * HD + akc * 8]);
#pragma unroll
        for (int j = 0; j < 2; ++j) {
            const int kc = bk0 + j;
            *reinterpret_cast<short8_t*>(&BhS[0][kc][bn][0]) =
                *reinterpret_cast<const short8_t*>(&Wh[(size_t)(n0 + bn) * HD + kc * 8]);
            *reinterpret_cast<short8_t*>(&BlS[0][kc][bn][0]) =
                *reinterpret_cast<const short8_t*>(&Wl[(size_t)(n0 + bn) * HD + kc * 8]);
        }
    }
    __syncthreads();

    f32x4 acc[2][4];
#pragma unroll
    for (int mi = 0; mi < 2; ++mi)
#pragma unroll
        for (int ni = 0; ni < 4; ++ni)
            acc[mi][ni] = (f32x4){0.f, 0.f, 0.f, 0.f};

    for (int ks = 0; ks < 8; ++ks) {
        const int cur = ks & 1;
        short8_t rah, ral, rbh[2], rbl[2];
        if (ks < 7) {
            const int k1 = (ks + 1) * 32;
            rah = *reinterpret_cast<const short8_t*>(&Ah[(size_t)(m0 + ar) * HD + k1 + akc * 8]);
            ral = *reinterpret_cast<const short8_t*>(&Al[(size_t)(m0 + ar) * HD + k1 + akc * 8]);
#pragma unroll
            for (int j = 0; j < 2; ++j) {
                const int kc = bk0 + j;
                rbh[j] = *reinterpret_cast<const short8_t*>(&Wh[(size_t)(n0 + bn) * HD + k1 + kc * 8]);
                rbl[j] = *reinterpret_cast<const short8_t*>(&Wl[(size_t)(n0 + bn) * HD + k1 + kc * 8]);
            }
        }
        short8_t ahf[2], alf[2], bhf[4], blf[4];
#pragma unroll
        for (int mi = 0; mi < 2; ++mi) {
            ahf[mi] = *reinterpret_cast<const short8_t*>(&AhS[cur][lg][wr * 32 + mi * 16 + lr][0]);
            alf[mi] = *reinterpret_cast<const short8_t*>(&AlS[cur][lg][wr * 32 + mi * 16 + lr][0]);
        }
#pragma unroll
        for (int ni = 0; ni < 4; ++ni) {
            bhf[ni] = *reinterpret_cast<const short8_t*>(&BhS[cur][lg][wc * 64 + ni * 16 + lr][0]);
            blf[ni] = *reinterpret_cast<const short8_t*>(&BlS[cur][lg][wc * 64 + ni * 16 + lr][0]);
        }
#pragma unroll
        for (int mi = 0; mi < 2; ++mi)
#pragma unroll
            for (int ni = 0; ni < 4; ++ni) {
                acc[mi][ni] = __builtin_amdgcn_mfma_f32_16x16x32_bf16(ahf[mi], bhf[ni], acc[mi][ni], 0, 0, 0);
                acc[mi][ni] = __builtin_amdgcn_mfma_f32_16x16x32_bf16(ahf[mi], blf[ni], acc[mi][ni], 0, 0, 0);
                acc[mi][ni] = __builtin_amdgcn_mfma_f32_16x16x32_bf16(alf[mi], bhf[ni], acc[mi][ni], 0, 0, 0);
            }
        if (ks < 7) {
            const int nxt = cur ^ 1;
            *reinterpret_cast<short8_t*>(&AhS[nxt][akc][ar][0]) = rah;
            *reinterpret_cast<short8_t*>(&AlS[nxt][akc][ar][0]) = ral;
#pragma unroll
            for (int j = 0; j < 2; ++j) {
                const int kc = bk0 + j;
                *reinterpret_cast<short8_t*>(&BhS[nxt][kc][bn][0]) = rbh[j];
                *reinterpret_cast<short8_t*>(&BlS[nxt][kc][bn][0]) = rbl[j];
            }
        }
        __syncthreads();
    }

    const bool is_sg = (n0 >= 256);
    float bv[4];
    int cc[4];
#pragma unroll
    for (int ni = 0; ni < 4; ++ni) {
        const int dpk = n0 + wc * 64 + ni * 16 + lr;
        cc[ni] = is_sg ? dpk - 256 : dpk;
        bv[ni] = is_sg ? bsg[cc[ni]] : bmu[cc[ni]];
    }
    float* outp = is_sg ? osg : omu;
#pragma unroll
    for (int mi = 0; mi < 2; ++mi)
#pragma unroll
        for (int r = 0; r < 4; ++r) {
            const int row = m0 + wr * 32 + mi * 16 + lg * 4 + r;
#pragma unroll
            for (int ni = 0; ni < 4; ++ni) {
                const float v = acc[mi][ni][r] + bv[ni];
                outp[(size_t)row * HD + cc[ni]] = is_sg ? expf(v) : v;
            }
        }
}

// ---------------------------------------------------------------------------
// gating (unchanged from R5)
// ---------------------------------------------------------------------------
__global__ __launch_bounds__(256) void gate_kernel(
    const float* __restrict__ o_tmu, const float* __restrict__ o_tsig,
    const float* __restrict__ o_imu, const float* __restrict__ o_isig,
    const float* __restrict__ noise_t, const float* __restrict__ noise_i,
    const float* __restrict__ Wg, const float* __restrict__ bg,
    float* __restrict__ t_gate, float* __restrict__ i_gate,
    unsigned short* __restrict__ tzb, unsigned short* __restrict__ izb)
{
    const int mod = blockIdx.y;
    const float* mu    = mod ? o_imu  : o_tmu;
    const float* sig   = mod ? o_isig : o_tsig;
    const float* noise = mod ? noise_i : noise_t;
    float* gate        = mod ? i_gate : t_gate;
    unsigned short* zb = mod ? izb : tzb;

    const int lane = threadIdx.x & 63;
    const int n = blockIdx.x * 4 + (threadIdx.x >> 6);
    const size_t off = (size_t)n * HD + lane * 4;
    const float4 m4 = *reinterpret_cast<const float4*>(&mu[off]);
    const float4 s4 = *reinterpret_cast<const float4*>(&sig[off]);
    const float4 n4 = *reinterpret_cast<const float4*>(&noise[off]);
    const float zz[4] = { fmaf(s4.x, n4.x, m4.x), fmaf(s4.y, n4.y, m4.y),
                          fmaf(s4.z, n4.z, m4.z), fmaf(s4.w, n4.w, m4.w) };
    ushort4 zb4;
    zb4.x = f2b(zz[0]); zb4.y = f2b(zz[1]); zb4.z = f2b(zz[2]); zb4.w = f2b(zz[3]);
    *reinterpret_cast<ushort4*>(&zb[off]) = zb4;

    float lg[8];
#pragma unroll
    for (int e = 0; e < 8; ++e) lg[e] = 0.f;
#pragma unroll
    for (int i = 0; i < 4; ++i) {
        const float* wr = &Wg[(size_t)(lane * 4 + i) * 8];
        const float4 w0 = *reinterpret_cast<const float4*>(wr);
        const float4 w1 = *reinterpret_cast<const float4*>(wr + 4);
        lg[0] = fmaf(zz[i], w0.x, lg[0]); lg[1] = fmaf(zz[i], w0.y, lg[1]);
        lg[2] = fmaf(zz[i], w0.z, lg[2]); lg[3] = fmaf(zz[i], w0.w, lg[3]);
        lg[4] = fmaf(zz[i], w1.x, lg[4]); lg[5] = fmaf(zz[i], w1.y, lg[5]);
        lg[6] = fmaf(zz[i], w1.z, lg[6]); lg[7] = fmaf(zz[i], w1.w, lg[7]);
    }
#pragma unroll
    for (int off2 = 32; off2; off2 >>= 1)
#pragma unroll
        for (int e = 0; e < 8; ++e) lg[e] += __shfl_down(lg[e], off2);

    if (lane == 0) {
        float m = -1e30f;
#pragma unroll
        for (int e = 0; e < 8; ++e) { lg[e] += bg[e]; m = fmaxf(m, lg[e]); }
        float p[8], s = 0.f;
#pragma unroll
        for (int e = 0; e < 8; ++e) { p[e] = expf(lg[e] - m); s += p[e]; }
        const float inv_s = 1.f / s;
#pragma unroll
        for (int e = 0; e < 8; ++e) p[e] *= inv_s;
        int e1 = 0;
#pragma unroll
        for (int e = 1; e < 8; ++e) if (p[e] > p[e1]) e1 = e;
        int e2 = (e1 == 0) ? 1 : 0;
#pragma unroll
        for (int e = 0; e < 8; ++e) if (e != e1 && p[e] > p[e2]) e2 = e;
        const float denom = 1.f / (p[e1] + p[e2] + 1e-8f);
        float g[8];
#pragma unroll
        for (int e = 0; e < 8; ++e) g[e] = 0.f;
        g[e1] = p[e1] * denom; g[e2] = p[e2] * denom;
        float* gr = &gate[(size_t)n * 8];
        *reinterpret_cast<float4*>(gr)     = make_float4(g[0], g[1], g[2], g[3]);
        *reinterpret_cast<float4*>(gr + 4) = make_float4(g[4], g[5], g[6], g[7]);
    }
}

// ---------------------------------------------------------------------------
// experts v3 (m97 structure): 128x128 tile, 4 waves 2x2, 4x4 frags,
// global_load_lds dbuf staging for A and B, flat (e,ks) loop, 1 barrier/step.
// LDS linear layout chunk = row*4 + kc (exactly the glds lane order).
// ---------------------------------------------------------------------------
__global__ __launch_bounds__(256) void expert_mfma_kernel(
    const unsigned short* __restrict__ tzb, const unsigned short* __restrict__ izb,
    const unsigned short* __restrict__ wt_t, const unsigned short* __restrict__ wt_i,
    const float* __restrict__ bx_t, const float* __restrict__ bx_i,
    const float* __restrict__ g_t, const float* __restrict__ g_i,
    unsigned short* __restrict__ out_t, unsigned short* __restrict__ out_i)
{
    const int mod = blockIdx.z;
    const unsigned short* Zb = mod ? izb : tzb;
    const unsigned short* Wt = mod ? wt_i : wt_t;
    const float* bx   = mod ? bx_i : bx_t;
    const float* gate = mod ? g_i  : g_t;
    unsigned short* outp = mod ? out_i : out_t;

    __shared__ __align__(16) unsigned short Ab[2][512][8];  // 16 KB (128 rows x 32 k)
    __shared__ __align__(16) unsigned short Bb[2][512][8];  // 16 KB
    __shared__ float gld[128][8];                           //  4 KB

    const int tid = threadIdx.x;
    const int lane = tid & 63;
    const int w = tid >> 6;
    const int wr = w >> 1, wc = w & 1;
    const int lg = lane >> 4;
    const int lr = lane & 15;
    const int m0 = blockIdx.x * 128;
    const int n0 = blockIdx.y * 128;

    // gate tile (coalesced float4)
    reinterpret_cast<float4*>(&gld[0][0])[tid] =
        reinterpret_cast<const float4*>(&gate[(size_t)m0 * 8])[tid];

    // per-thread glds source rows: chunk = i*256 + w*64 + lane
    const int c0 = w * 64 + lane;
    const int row0 = c0 >> 2,          kc0 = c0 & 3;
    const int row1 = (c0 + 256) >> 2,  kc1 = (c0 + 256) & 3;

#define STAGE(buf, e_, ks_)                                                    \
    {                                                                          \
        const unsigned short* We_ = Wt + (size_t)(e_) * 65536 + (size_t)n0 * HD;\
        glds16(&Zb[(size_t)(m0 + row0) * HD + (ks_) * 32 + kc0 * 8],           \
               &Ab[buf][w * 64][0]);                                           \
        glds16(&Zb[(size_t)(m0 + row1) * HD + (ks_) * 32 + kc1 * 8],           \
               &Ab[buf][256 + w * 64][0]);                                     \
        glds16(&We_[(size_t)row0 * HD + (ks_) * 32 + kc0 * 8],                 \
               &Bb[buf][w * 64][0]);                                           \
        glds16(&We_[(size_t)row1 * HD + (ks_) * 32 + kc1 * 8],                 \
               &Bb[buf][256 + w * 64][0]);                                     \
    }

    STAGE(0, 0, 0);
    __syncthreads();

    f32x4 acc[4][4], accT[4][4];
#pragma unroll
    for (int mi = 0; mi < 4; ++mi)
#pragma unroll
        for (int ni = 0; ni < 4; ++ni) {
            acc[mi][ni]  = (f32x4){0.f, 0.f, 0.f, 0.f};
            accT[mi][ni] = (f32x4){0.f, 0.f, 0.f, 0.f};
        }

    for (int kk = 0; kk < 64; ++kk) {
        const int cur = kk & 1;
        const int e = kk >> 3, ks = kk & 7;
        if (kk < 63) {
            const int e2 = (kk + 1) >> 3, ks2 = (kk + 1) & 7;
            STAGE(cur ^ 1, e2, ks2);
        }
        short8_t af[4], bf[4];
#pragma unroll
        for (int mi = 0; mi < 4; ++mi)
            af[mi] = *reinterpret_cast<const short8_t*>(
                &Ab[cur][(wr * 64 + mi * 16 + lr) * 4 + lg][0]);
#pragma unroll
        for (int ni = 0; ni < 4; ++ni)
            bf[ni] = *reinterpret_cast<const short8_t*>(
                &Bb[cur][(wc * 64 + ni * 16 + lr) * 4 + lg][0]);
#pragma unroll
        for (int mi = 0; mi < 4; ++mi)
#pragma unroll
            for (int ni = 0; ni < 4; ++ni)
                acc[mi][ni] = __builtin_amdgcn_mfma_f32_16x16x32_bf16(
                    af[mi], bf[ni], acc[mi][ni], 0, 0, 0);
        if (ks == 7) {
#pragma unroll
            for (int mi = 0; mi < 4; ++mi) {
                const int rb = wr * 64 + mi * 16 + lg * 4;
                const float gv0 = gld[rb + 0][e];
                const float gv1 = gld[rb + 1][e];
                const float gv2 = gld[rb + 2][e];
                const float gv3 = gld[rb + 3][e];
#pragma unroll
                for (int ni = 0; ni < 4; ++ni) {
                    const float bv = bx[(size_t)e * HD + n0 + wc * 64 + ni * 16 + lr];
                    accT[mi][ni][0] += gv0 * (acc[mi][ni][0] + bv);
                    accT[mi][ni][1] += gv1 * (acc[mi][ni][1] + bv);
                    accT[mi][ni][2] += gv2 * (acc[mi][ni][2] + bv);
                    accT[mi][ni][3] += gv3 * (acc[mi][ni][3] + bv);
                    acc[mi][ni] = (f32x4){0.f, 0.f, 0.f, 0.f};
                }
            }
        }
        __syncthreads();
    }
#undef STAGE

#pragma unroll
    for (int mi = 0; mi < 4; ++mi)
#pragma unroll
        for (int ni = 0; ni < 4; ++ni)
#pragma unroll
            for (int r = 0; r < 4; ++r)
                outp[(size_t)(m0 + wr * 64 + mi * 16 + lg * 4 + r) * HD
                     + n0 + wc * 64 + ni * 16 + lr] = f2b(accT[mi][ni][r]);
}

// ---------------------------------------------------------------------------
// fuse GEMM v2 (unchanged from R5)
// ---------------------------------------------------------------------------
__global__ __launch_bounds__(256) void fusegemm_mfma_kernel(
    const unsigned short* __restrict__ t_outb, const unsigned short* __restrict__ i_outb,
    const unsigned short* __restrict__ wtf, const float* __restrict__ bfuse,
    float* __restrict__ fused)
{
    __shared__ __align__(16) unsigned short AS[2][8][64][8];
    __shared__ __align__(16) unsigned short BS[2][8][128][8];

    const int tid = threadIdx.x;
    const int lane = tid & 63;
    const int w = tid >> 6;
    const int wr = w >> 1, wc = w & 1;
    const int lg = lane >> 4;
    const int lr = lane & 15;
    const int m0 = blockIdx.x * 64;
    const int n0 = blockIdx.y * 128;

    const int ar = tid >> 2, akc0 = (tid & 3) * 2;
    const int bn = tid >> 1, bkc0 = (tid & 1) * 4;

    {
        const unsigned short* base = t_outb;
#pragma unroll
        for (int j = 0; j < 2; ++j) {
            const int kc = akc0 + j;
            *reinterpret_cast<short8_t*>(&AS[0][kc][ar][0]) =
                *reinterpret_cast<const short8_t*>(&base[(size_t)(m0 + ar) * HD + kc * 8]);
        }
#pragma unroll
        for (int j = 0; j < 4; ++j) {
            const int kc = bkc0 + j;
            *reinterpret_cast<short8_t*>(&BS[0][kc][bn][0]) =
                *reinterpret_cast<const short8_t*>(&wtf[(size_t)(n0 + bn) * 512 + kc * 8]);
        }
    }
    __syncthreads();

    f32x4 acc[2][4];
#pragma unroll
    for (int mi = 0; mi < 2; ++mi)
#pragma unroll
        for (int ni = 0; ni < 4; ++ni)
            acc[mi][ni] = (f32x4){0.f, 0.f, 0.f, 0.f};

    for (int ks = 0; ks < 8; ++ks) {
        const int cur = ks & 1;
        short8_t ra[2], rbv[4];
        if (ks < 7) {
            const int ks2 = ks + 1;
            const unsigned short* base = (ks2 < 4) ? t_outb : i_outb;
            const int kloc = (ks2 & 3) * 64;
#pragma unroll
            for (int j = 0; j < 2; ++j) {
                const int kc = akc0 + j;
                ra[j] = *reinterpret_cast<const short8_t*>(
                    &base[(size_t)(m0 + ar) * HD + kloc + kc * 8]);
            }
#pragma unroll
            for (int j = 0; j < 4; ++j) {
                const int kc = bkc0 + j;
                rbv[j] = *reinterpret_cast<const short8_t*>(
                    &wtf[(size_t)(n0 + bn) * 512 + ks2 * 64 + kc * 8]);
            }
        }
#pragma unroll
        for (int s = 0; s < 2; ++s) {
            short8_t af[2], bf[4];
#pragma unroll
            for (int mi = 0; mi < 2; ++mi)
                af[mi] = *reinterpret_cast<const short8_t*>(
                    &AS[cur][s * 4 + lg][wr * 32 + mi * 16 + lr][0]);
#pragma unroll
            for (int ni = 0; ni < 4; ++ni)
                bf[ni] = *reinterpret_cast<const short8_t*>(
                    &BS[cur][s * 4 + lg][wc * 64 + ni * 16 + lr][0]);
#pragma unroll
            for (int mi = 0; mi < 2; ++mi)
#pragma unroll
                for (int ni = 0; ni < 4; ++ni)
                    acc[mi][ni] = __builtin_amdgcn_mfma_f32_16x16x32_bf16(
                        af[mi], bf[ni], acc[mi][ni], 0, 0, 0);
        }
        if (ks < 7) {
            const int nxt = cur ^ 1;
#pragma unroll
            for (int j = 0; j < 2; ++j)
                *reinterpret_cast<short8_t*>(&AS[nxt][akc0 + j][ar][0]) = ra[j];
#pragma unroll
            for (int j = 0; j < 4; ++j)
                *reinterpret_cast<short8_t*>(&BS[nxt][bkc0 + j][bn][0]) = rbv[j];
        }
        __syncthreads();
    }

    float bv[4];
    int cc[4];
#pragma unroll
    for (int ni = 0; ni < 4; ++ni) {
        cc[ni] = n0 + wc * 64 + ni * 16 + lr;
        bv[ni] = bfuse[cc[ni]];
    }
#pragma unroll
    for (int mi = 0; mi < 2; ++mi)
#pragma unroll
        for (int r = 0; r < 4; ++r) {
            const int row = m0 + wr * 32 + mi * 16 + lg * 4 + r;
#pragma unroll
            for (int ni = 0; ni < 4; ++ni)
                fused[(size_t)row * HD + cc[ni]] = acc[mi][ni][r] + bv[ni];
        }
}

// ---------------------------------------------------------------------------
// LN -> ReLU -> +item (unchanged)
// ---------------------------------------------------------------------------
__global__ __launch_bounds__(256) void ln_relu_res_kernel(
    const float* __restrict__ fused, const float* __restrict__ g,
    const float* __restrict__ b, const float* __restrict__ item,
    float* __restrict__ fusion)
{
    const int lane = threadIdx.x & 63;
    const int n = blockIdx.x * 4 + (threadIdx.x >> 6);
    const size_t off = (size_t)n * HD + lane * 4;
    const float4 x = *reinterpret_cast<const float4*>(&fused[off]);
    float s = x.x + x.y + x.z + x.w;
    float ss = x.x * x.x + x.y * x.y + x.z * x.z + x.w * x.w;
#pragma unroll
    for (int o = 32; o; o >>= 1) { s += __shfl_xor(s, o); ss += __shfl_xor(ss, o); }
    const float mean = s * (1.f / 256.f);
    const float var = ss * (1.f / 256.f) - mean * mean;
    const float rstd = rsqrtf(var + 1e-5f);
    const float4 gg = *reinterpret_cast<const float4*>(&g[lane * 4]);
    const float4 bb = *reinterpret_cast<const float4*>(&b[lane * 4]);
    const float4 it = *reinterpret_cast<const float4*>(&item[off]);
    float4 o4;
    o4.x = fmaxf((x.x - mean) * rstd * gg.x + bb.x, 0.f) + it.x;
    o4.y = fmaxf((x.y - mean) * rstd * gg.y + bb.y, 0.f) + it.y;
    o4.z = fmaxf((x.z - mean) * rstd * gg.z + bb.z, 0.f) + it.z;
    o4.w = fmaxf((x.w - mean) * rstd * gg.w + bb.w, 0.f) + it.w;
    *reinterpret_cast<float4*>(&fusion[off]) = o4;
}

// ---------------------------------------------------------------------------
extern "C" void kernel_launch(void* const* d_in, const int* in_sizes, int n_in,
                              void* d_out, int out_size, void* d_ws, size_t ws_size,
                              hipStream_t stream)
{
    const float* text    = (const float*)d_in[0];
    const float* img     = (const float*)d_in[1];
    const float* item    = (const float*)d_in[2];
    const float* noise_t = (const float*)d_in[3];
    const float* noise_i = (const float*)d_in[4];
    const float* W_mu_t  = (const float*)d_in[5];
    const float* b_mu_t  = (const float*)d_in[6];
    const float* W_sg_t  = (const float*)d_in[7];
    const float* b_sg_t  = (const float*)d_in[8];
    const float* W_mu_i  = (const float*)d_in[9];
    const float* b_mu_i  = (const float*)d_in[10];
    const float* W_sg_i  = (const float*)d_in[11];
    const float* b_sg_i  = (const float*)d_in[12];
    const float* W_gate  = (const float*)d_in[13];
    const float* b_gate  = (const float*)d_in[14];
    const float* W_texp  = (const float*)d_in[15];
    const float* b_texp  = (const float*)d_in[16];
    const float* W_iexp  = (const float*)d_in[17];
    const float* b_iexp  = (const float*)d_in[18];
    const float* W_fuse  = (const float*)d_in[19];
    const float* b_fuse  = (const float*)d_in[20];
    const float* ln_g    = (const float*)d_in[21];
    const float* ln_b    = (const float*)d_in[22];

    float* out    = (float*)d_out;
    float* fusion = out;
    float* o_tmu  = out + (size_t)SOUT;
    float* o_tsig = out + (size_t)2 * SOUT;
    float* o_imu  = out + (size_t)3 * SOUT;
    float* o_isig = out + (size_t)4 * SOUT;

    unsigned short* bufA = (unsigned short*)d_ws;
    unsigned short* bufB = bufA + (size_t)SOUT;
    unsigned short* bufC = bufB + (size_t)SOUT;
    unsigned short* tzb  = bufC + (size_t)2 * SOUT;
    unsigned short* izb  = tzb + (size_t)SOUT;
    float* t_gate = (float*)(izb + (size_t)SOUT);
    float* i_gate = t_gate + (size_t)NTOK * 8;
    unsigned short* wt_t   = (unsigned short*)(i_gate + (size_t)NTOK * 8);
    unsigned short* wt_i   = wt_t + (size_t)8 * 65536;
    unsigned short* wt_f   = wt_i + (size_t)8 * 65536;
    unsigned short* wpk_th = wt_f + (size_t)131072;
    unsigned short* wpk_tl = wpk_th + (size_t)131072;
    unsigned short* wpk_ih = wpk_tl + (size_t)131072;
    unsigned short* wpk_il = wpk_ih + (size_t)131072;

    unsigned short* ah_t = bufA;
    unsigned short* al_t = bufB;
    unsigned short* ah_i = bufC;
    unsigned short* al_i = bufC + (size_t)SOUT;
    unsigned short* t_outb = bufA;
    unsigned short* i_outb = bufB;
    float* fused = (float*)bufC;

    prepW_kernel<<<dim3(16, 22), 256, 0, stream>>>(
        W_texp, W_iexp, W_mu_t, W_sg_t, W_mu_i, W_sg_i, W_fuse,
        wt_t, wt_i, wt_f, wpk_th, wpk_tl, wpk_ih, wpk_il);

    cvt_kernel<<<dim3(SOUT / 2048, 2), 256, 0, stream>>>(
        text, img, ah_t, al_t, ah_i, al_i);

    reparam_mfma_kernel<<<dim3(NTOK / 64, 4, 2), 256, 0, stream>>>(
        ah_t, al_t, ah_i, al_i, wpk_th, wpk_tl, wpk_ih, wpk_il,
        b_mu_t, b_sg_t, b_mu_i, b_sg_i,
        o_tmu, o_tsig, o_imu, o_isig);

    gate_kernel<<<dim3(NTOK / 4, 2), 256, 0, stream>>>(
        o_tmu, o_tsig, o_imu, o_isig, noise_t, noise_i,
        W_gate, b_gate, t_gate, i_gate, tzb, izb);

    expert_mfma_kernel<<<dim3(NTOK / 128, 2, 2), 256, 0, stream>>>(
        tzb, izb, wt_t, wt_i, b_texp, b_iexp, t_gate, i_gate, t_outb, i_outb);

    fusegemm_mfma_kernel<<<dim3(NTOK / 64, 2), 256, 0, stream>>>(
        t_outb, i_outb, wt_f, b_fuse, fused);

    ln_relu_res_kernel<<<NTOK / 4, 256, 0, stream>>>(fused, ln_g, ln_b, item, fusion);
}